// Round 1
// baseline (330.785 us; speedup 1.0000x reference)
//
#include <hip/hip_runtime.h>
#include <math.h>

// Problem constants: B=8, H=8 (BH=64 heads), N=4096, D=64, M=64, 6 NS iters.
#define NSEQ 4096

// workspace offsets (in floats)
#define OFF_SUMK 0u
#define OFF_SUMQ 262144u
#define OFF_NC   524288u
#define OFF_NR   786432u
#define OFF_U    1048576u
#define OFF_VM   1310720u
#define OFF_W    1572864u
#define OFF_PRV  1835008u      // 64 heads * 8 chunks * 64 * 64
#define OFF_PMAX 3932160u      // 64*8*64
#define OFF_PSUM 3964928u
#define OFF_HMAX 3997696u      // 64
#define OFF_GMAX 3997760u      // 1
// total ~16.0 MB of d_ws

// ---------- helpers ----------

// Load a 64x64 row-major matrix from global, store TRANSPOSED (col-major of src)
// dst[k*64+m] = src[m*64+k]
__device__ __forceinline__ void loadT64(float* dst, const float* __restrict__ src, int t) {
    for (int e = t; e < 1024; e += 256) {
        int m = e >> 4, k0 = (e & 15) << 2;
        float4 v = *(const float4*)(src + m * 64 + k0);
        dst[(k0 + 0) * 64 + m] = v.x;
        dst[(k0 + 1) * 64 + m] = v.y;
        dst[(k0 + 2) * 64 + m] = v.z;
        dst[(k0 + 3) * 64 + m] = v.w;
    }
}

// acc[r][c] += sum_k Acm[k*64+i0+r] * Brm[k*64+j0+c]
// (A_eff[i][k] = Acm[k*64+i], B_eff[k][j] = Brm[k*64+j])
__device__ __forceinline__ void mm64add(const float* Acm, const float* Brm,
                                        float acc[4][4], int i0, int j0) {
#pragma unroll 8
    for (int k = 0; k < 64; k++) {
        float4 a = *(const float4*)(Acm + k * 64 + i0);
        float4 b = *(const float4*)(Brm + k * 64 + j0);
        acc[0][0] += a.x * b.x; acc[0][1] += a.x * b.y; acc[0][2] += a.x * b.z; acc[0][3] += a.x * b.w;
        acc[1][0] += a.y * b.x; acc[1][1] += a.y * b.y; acc[1][2] += a.y * b.z; acc[1][3] += a.y * b.w;
        acc[2][0] += a.z * b.x; acc[2][1] += a.z * b.y; acc[2][2] += a.z * b.z; acc[2][3] += a.z * b.w;
        acc[3][0] += a.w * b.x; acc[3][1] += a.w * b.y; acc[3][2] += a.w * b.z; acc[3][3] += a.w * b.w;
    }
}

__device__ __forceinline__ void mm64(const float* Acm, const float* Brm,
                                     float acc[4][4], int i0, int j0) {
#pragma unroll
    for (int r = 0; r < 4; r++)
#pragma unroll
        for (int c = 0; c < 4; c++) acc[r][c] = 0.f;
    mm64add(Acm, Brm, acc, i0, j0);
}

__device__ __forceinline__ void writeN64(float* dst, const float acc[4][4], int i0, int j0, float s) {
#pragma unroll
    for (int r = 0; r < 4; r++) {
        float4 v;
        v.x = s * acc[r][0]; v.y = s * acc[r][1]; v.z = s * acc[r][2]; v.w = s * acc[r][3];
        *(float4*)(dst + (i0 + r) * 64 + j0) = v;
    }
}

__device__ __forceinline__ void writeT64(float* dst, const float acc[4][4], int i0, int j0, float s) {
#pragma unroll
    for (int c = 0; c < 4; c++) {
        float4 v;
        v.x = s * acc[0][c]; v.y = s * acc[1][c]; v.z = s * acc[2][c]; v.w = s * acc[3][c];
        *(float4*)(dst + (j0 + c) * 64 + i0) = v;
    }
}

// ---------- kernel A: row sums of Q and K ----------
__global__ __launch_bounds__(256) void k_sums(const float* __restrict__ Qg,
                                              const float* __restrict__ Kg, float* ws) {
    size_t row = (size_t)blockIdx.x * 64 + (threadIdx.x >> 2);
    int q = threadIdx.x & 3;
    const float4* qp = (const float4*)(Qg + row * 64 + q * 16);
    const float4* kp = (const float4*)(Kg + row * 64 + q * 16);
    float s1 = 0.f, s2 = 0.f;
#pragma unroll
    for (int i = 0; i < 4; i++) { float4 v = qp[i]; s1 += (v.x + v.y) + (v.z + v.w); }
#pragma unroll
    for (int i = 0; i < 4; i++) { float4 v = kp[i]; s2 += (v.x + v.y) + (v.z + v.w); }
    s1 += __shfl_xor(s1, 1); s1 += __shfl_xor(s1, 2);
    s2 += __shfl_xor(s2, 1); s2 += __shfl_xor(s2, 2);
    if (q == 0) { ws[OFF_SUMQ + row] = s1; ws[OFF_SUMK + row] = s2; }
}

// ---------- kernel B: top-64 select (stable desc) + gather ----------
__global__ __launch_bounds__(256) void k_select(const float* __restrict__ Qg,
                                                const float* __restrict__ Kg, float* ws) {
    int head = blockIdx.x, sel = blockIdx.y, t = threadIdx.x;
    __shared__ float sc[4096];
    __shared__ unsigned long long wred[4];
    __shared__ int idx_s[64];
    const float* scores = ws + (sel ? OFF_SUMQ : OFF_SUMK) + (size_t)head * 4096;
    for (int i = t; i < 4096; i += 256) sc[i] = scores[i];
    __syncthreads();
    int lane = t & 63, wid = t >> 6;
    for (int m = 0; m < 64; m++) {
        unsigned long long best = 0ull;
#pragma unroll
        for (int i = 0; i < 16; i++) {
            int e = i * 256 + t;
            unsigned uu = __float_as_uint(sc[e]);
            uu = (uu & 0x80000000u) ? ~uu : (uu | 0x80000000u);
            unsigned long long key = ((unsigned long long)uu << 32) |
                                     (unsigned)(0xFFFFFFFFu - (unsigned)e);
            if (key > best) best = key;
        }
#pragma unroll
        for (int s = 1; s < 64; s <<= 1) {
            unsigned long long o = __shfl_xor(best, s);
            if (o > best) best = o;
        }
        if (lane == 0) wred[wid] = best;
        __syncthreads();
        if (t == 0) {
            unsigned long long b = wred[0];
            if (wred[1] > b) b = wred[1];
            if (wred[2] > b) b = wred[2];
            if (wred[3] > b) b = wred[3];
            int widx = (int)(0xFFFFFFFFu - (unsigned)(b & 0xFFFFFFFFull));
            idx_s[m] = widx;
            sc[widx] = -INFINITY;
        }
        __syncthreads();
    }
    const float* src = sel ? Qg : Kg;
    float* dst = ws + (sel ? OFF_NR : OFF_NC) + (size_t)head * 4096;
    float scl = sel ? 0.125f : 1.0f;
    for (int e = t; e < 4096; e += 256) {
        int m = e >> 6, d = e & 63;
        dst[e] = src[((size_t)head * NSEQ + (size_t)idx_s[m]) * 64 + d] * scl;
    }
}

// ---------- kernel C: u = softmax(nr @ nc^T) + per-head max colsum ----------
__global__ __launch_bounds__(256) void k_u(float* ws) {
    int head = blockIdx.x, t = threadIdx.x;
    __shared__ __align__(16) float A_s[4096];
    __shared__ __align__(16) float B_s[4096];
    __shared__ float colpart[1024];
    loadT64(A_s, ws + OFF_NR + (size_t)head * 4096, t);
    loadT64(B_s, ws + OFF_NC + (size_t)head * 4096, t);
    __syncthreads();
    int ti = t >> 4, tj = t & 15, i0 = ti << 2, j0 = tj << 2;
    float acc[4][4];
    mm64(A_s, B_s, acc, i0, j0);
#pragma unroll
    for (int r = 0; r < 4; r++) {
        float m0 = fmaxf(fmaxf(acc[r][0], acc[r][1]), fmaxf(acc[r][2], acc[r][3]));
        m0 = fmaxf(m0, __shfl_xor(m0, 1)); m0 = fmaxf(m0, __shfl_xor(m0, 2));
        m0 = fmaxf(m0, __shfl_xor(m0, 4)); m0 = fmaxf(m0, __shfl_xor(m0, 8));
        float s = 0.f;
#pragma unroll
        for (int c = 0; c < 4; c++) { acc[r][c] = __expf(acc[r][c] - m0); s += acc[r][c]; }
        s += __shfl_xor(s, 1); s += __shfl_xor(s, 2);
        s += __shfl_xor(s, 4); s += __shfl_xor(s, 8);
#pragma unroll
        for (int c = 0; c < 4; c++) acc[r][c] = acc[r][c] / s;
    }
    float* u = ws + OFF_U + (size_t)head * 4096;
#pragma unroll
    for (int r = 0; r < 4; r++) {
        float4 v; v.x = acc[r][0]; v.y = acc[r][1]; v.z = acc[r][2]; v.w = acc[r][3];
        *(float4*)(u + (i0 + r) * 64 + j0) = v;
    }
#pragma unroll
    for (int c = 0; c < 4; c++)
        colpart[ti * 64 + j0 + c] = acc[0][c] + acc[1][c] + acc[2][c] + acc[3][c];
    __syncthreads();
    if (t < 64) {
        float cs = 0.f;
#pragma unroll
        for (int g = 0; g < 16; g++) cs += colpart[g * 64 + t];
        float v = cs;
#pragma unroll
        for (int s = 1; s < 64; s <<= 1) v = fmaxf(v, __shfl_xor(v, s));
        if (t == 0) ws[OFF_HMAX + head] = v;
    }
}

// ---------- kernel D: global max over head colsum maxima ----------
__global__ void k_gmax(float* ws) {
    int t = threadIdx.x;
    float v = ws[OFF_HMAX + t];
#pragma unroll
    for (int s = 1; s < 64; s <<= 1) v = fmaxf(v, __shfl_xor(v, s));
    if (t == 0) ws[OFF_GMAX] = v;
}

// ---------- kernel E: Newton-Schulz iterative inverse (per head) ----------
__global__ __launch_bounds__(256) void k_nsinv(float* ws) {
    int head = blockIdx.x, t = threadIdx.x;
    __shared__ __align__(16) float KmCm[4096];  // Km col-major: [k][i]
    __shared__ __align__(16) float VmCm[4096];  // VmT row-major (= Vm col-major)
    __shared__ __align__(16) float KVCm[4096];  // KV col-major
    __shared__ __align__(16) float Sh[4096];    // Vm_rm -> KV_rm -> M2 -> M2b -> Vm'_rm
    const float* u = ws + OFF_U + (size_t)head * 4096;
    float g = ws[OFF_GMAX];
    for (int e = t; e < 1024; e += 256) {
        int i = e >> 4, k0 = (e & 15) << 2;
        float4 v = *(const float4*)(u + i * 64 + k0);
        KmCm[(k0 + 0) * 64 + i] = v.x; KmCm[(k0 + 1) * 64 + i] = v.y;
        KmCm[(k0 + 2) * 64 + i] = v.z; KmCm[(k0 + 3) * 64 + i] = v.w;
        Sh[(k0 + 0) * 64 + i] = v.x / g; Sh[(k0 + 1) * 64 + i] = v.y / g;
        Sh[(k0 + 2) * 64 + i] = v.z / g; Sh[(k0 + 3) * 64 + i] = v.w / g;
        float4 w; w.x = v.x / g; w.y = v.y / g; w.z = v.z / g; w.w = v.w / g;
        *(float4*)(VmCm + i * 64 + k0) = w;
    }
    __syncthreads();
    int ti = t >> 4, tj = t & 15, i0 = ti << 2, j0 = tj << 2;
    float acc[4][4], corr[4][4];
    for (int it = 0; it < 6; it++) {
        // s1: KV = Km @ Vm
        mm64(KmCm, Sh, acc, i0, j0);
        __syncthreads();
        writeN64(Sh, acc, i0, j0, 1.f);     // Sh = KV (row-major)
        writeT64(KVCm, acc, i0, j0, 1.f);   // KVCm = KV col-major
        __syncthreads();
        // s2: M2 = 7*KV - KV@KV
        mm64(KVCm, Sh, acc, i0, j0);
#pragma unroll
        for (int r = 0; r < 4; r++)
#pragma unroll
            for (int c = 0; c < 4; c++) corr[r][c] = Sh[(i0 + r) * 64 + j0 + c];
        __syncthreads();
#pragma unroll
        for (int r = 0; r < 4; r++)
#pragma unroll
            for (int c = 0; c < 4; c++) acc[r][c] = 7.f * corr[r][c] - acc[r][c];
        writeN64(Sh, acc, i0, j0, 1.f);     // Sh = M2
        __syncthreads();
        // s3: M2b = 15*KV - KV@M2
        mm64(KVCm, Sh, acc, i0, j0);
#pragma unroll
        for (int r = 0; r < 4; r++)
#pragma unroll
            for (int c = 0; c < 4; c++) corr[r][c] = KVCm[(j0 + c) * 64 + i0 + r]; // KV[i][j]
        __syncthreads();
#pragma unroll
        for (int r = 0; r < 4; r++)
#pragma unroll
            for (int c = 0; c < 4; c++) acc[r][c] = 15.f * corr[r][c] - acc[r][c];
        writeN64(Sh, acc, i0, j0, 1.f);     // Sh = M2b
        __syncthreads();
        // s4: VmT' = 0.25*(13*VmT - M2bT @ VmT)
        mm64(Sh, VmCm, acc, i0, j0);
#pragma unroll
        for (int r = 0; r < 4; r++)
#pragma unroll
            for (int c = 0; c < 4; c++) corr[r][c] = VmCm[(i0 + r) * 64 + j0 + c]; // VmT[i][j]
        __syncthreads();
#pragma unroll
        for (int r = 0; r < 4; r++)
#pragma unroll
            for (int c = 0; c < 4; c++) acc[r][c] = 0.25f * (13.f * corr[r][c] - acc[r][c]);
        writeN64(VmCm, acc, i0, j0, 1.f);   // new VmT (row-major)
        writeT64(Sh, acc, i0, j0, 1.f);     // new Vm (row-major)
        __syncthreads();
    }
    float* vm = ws + OFF_VM + (size_t)head * 4096;
    for (int e = t; e < 1024; e += 256) {
        int i = e >> 4, k0 = (e & 15) << 2;
        *(float4*)(vm + i * 64 + k0) = *(const float4*)(Sh + i * 64 + k0);
    }
}

// ---------- kernel F: partial flash softmax(nr@K^T) @ V per (head, chunk) ----------
__global__ __launch_bounds__(256) void k_rvp(const float* __restrict__ Kg,
                                             const float* __restrict__ Vg, float* ws) {
    int head = blockIdx.x, ch = blockIdx.y, t = threadIdx.x;
    __shared__ __align__(16) float nrCm[4096];
    __shared__ __align__(16) float KVs[4096];  // K^T subtile, then V subtile
    __shared__ __align__(16) float Pcm[4096];  // exp-probs col-major
    loadT64(nrCm, ws + OFF_NR + (size_t)head * 4096, t);
    int ti = t >> 4, tj = t & 15, i0 = ti << 2, j0 = tj << 2;
    float rv[4][4];
#pragma unroll
    for (int r = 0; r < 4; r++)
#pragma unroll
        for (int c = 0; c < 4; c++) rv[r][c] = 0.f;
    float mrow[4] = {-INFINITY, -INFINITY, -INFINITY, -INFINITY};
    float srow[4] = {0.f, 0.f, 0.f, 0.f};
    const float* Kbase = Kg + ((size_t)head * NSEQ + (size_t)ch * 512) * 64;
    const float* Vbase = Vg + ((size_t)head * NSEQ + (size_t)ch * 512) * 64;
    for (int s8 = 0; s8 < 8; s8++) {
        __syncthreads();                       // prev PV done (covers nrCm on iter 0)
        loadT64(KVs, Kbase + s8 * 4096, t);    // KVs[k][n] = K[n][k]
        __syncthreads();
        float sacc[4][4];
        mm64(nrCm, KVs, sacc, i0, j0);         // S[m][n] = nr @ K^T
        float p[4][4], scl[4];
#pragma unroll
        for (int r = 0; r < 4; r++) {
            float m0 = fmaxf(fmaxf(sacc[r][0], sacc[r][1]), fmaxf(sacc[r][2], sacc[r][3]));
            m0 = fmaxf(m0, __shfl_xor(m0, 1)); m0 = fmaxf(m0, __shfl_xor(m0, 2));
            m0 = fmaxf(m0, __shfl_xor(m0, 4)); m0 = fmaxf(m0, __shfl_xor(m0, 8));
            float mnew = fmaxf(mrow[r], m0);
            float sc = __expf(mrow[r] - mnew);
            float ps = 0.f;
#pragma unroll
            for (int c = 0; c < 4; c++) { p[r][c] = __expf(sacc[r][c] - mnew); ps += p[r][c]; }
            ps += __shfl_xor(ps, 1); ps += __shfl_xor(ps, 2);
            ps += __shfl_xor(ps, 4); ps += __shfl_xor(ps, 8);
            srow[r] = srow[r] * sc + ps;
            mrow[r] = mnew;
            scl[r] = sc;
        }
#pragma unroll
        for (int r = 0; r < 4; r++)
#pragma unroll
            for (int c = 0; c < 4; c++) rv[r][c] *= scl[r];
        __syncthreads();                       // all done reading KVs(K)
        for (int e = t; e < 1024; e += 256) {  // V straight copy
            int n = e >> 4, k0 = (e & 15) << 2;
            *(float4*)(KVs + n * 64 + k0) = *(const float4*)(Vbase + s8 * 4096 + n * 64 + k0);
        }
        writeT64(Pcm, p, i0, j0, 1.f);
        __syncthreads();
        mm64add(Pcm, KVs, rv, i0, j0);         // rv += P @ V
    }
    size_t pb = (size_t)(head * 8 + ch) * 64;
    if (tj == 0) {
#pragma unroll
        for (int r = 0; r < 4; r++) {
            ws[OFF_PMAX + pb + i0 + r] = mrow[r];
            ws[OFF_PSUM + pb + i0 + r] = srow[r];
        }
    }
#pragma unroll
    for (int r = 0; r < 4; r++) {
        float4 v; v.x = rv[r][0]; v.y = rv[r][1]; v.z = rv[r][2]; v.w = rv[r][3];
        *(float4*)(ws + OFF_PRV + (pb + i0 + r) * 64 + j0) = v;
    }
}

// ---------- kernel G: combine partials -> RV; W = k2inv @ RV ----------
__global__ __launch_bounds__(256) void k_comb(float* ws) {
    int head = blockIdx.x, t = threadIdx.x;
    __shared__ __align__(16) float A_s[4096];  // k2inv col-major
    __shared__ __align__(16) float B_s[4096];  // RV row-major
    loadT64(A_s, ws + OFF_VM + (size_t)head * 4096, t);
    int ti = t >> 4, tj = t & 15, i0 = ti << 2, j0 = tj << 2;
    const float* pm = ws + OFF_PMAX + (size_t)head * 512;
    const float* psv = ws + OFF_PSUM + (size_t)head * 512;
    const float* prv = ws + OFF_PRV + (size_t)head * 8 * 4096;
    float gm[4] = {-INFINITY, -INFINITY, -INFINITY, -INFINITY};
    for (int c8 = 0; c8 < 8; c8++)
#pragma unroll
        for (int r = 0; r < 4; r++) gm[r] = fmaxf(gm[r], pm[c8 * 64 + i0 + r]);
    float stot[4] = {0.f, 0.f, 0.f, 0.f};
    float racc[4][4];
#pragma unroll
    for (int r = 0; r < 4; r++)
#pragma unroll
        for (int c = 0; c < 4; c++) racc[r][c] = 0.f;
    for (int c8 = 0; c8 < 8; c8++) {
#pragma unroll
        for (int r = 0; r < 4; r++) {
            float w = __expf(pm[c8 * 64 + i0 + r] - gm[r]);
            stot[r] += w * psv[c8 * 64 + i0 + r];
            float4 v = *(const float4*)(prv + (size_t)(c8 * 64 + i0 + r) * 64 + j0);
            racc[r][0] += w * v.x; racc[r][1] += w * v.y;
            racc[r][2] += w * v.z; racc[r][3] += w * v.w;
        }
    }
#pragma unroll
    for (int r = 0; r < 4; r++)
#pragma unroll
        for (int c = 0; c < 4; c++) racc[r][c] /= stot[r];
    writeN64(B_s, racc, i0, j0, 1.f);
    __syncthreads();
    float acc[4][4];
    mm64(A_s, B_s, acc, i0, j0);
    float* Wo = ws + OFF_W + (size_t)head * 4096;
#pragma unroll
    for (int r = 0; r < 4; r++) {
        float4 v; v.x = acc[r][0]; v.y = acc[r][1]; v.z = acc[r][2]; v.w = acc[r][3];
        *(float4*)(Wo + (i0 + r) * 64 + j0) = v;
    }
}

// ---------- kernel H: X = softmax(Q@nc^T/8) @ W ----------
__global__ __launch_bounds__(256) void k_final(const float* __restrict__ Qg, float* ws,
                                               float* __restrict__ out) {
    int tile = blockIdx.x, head = blockIdx.y, t = threadIdx.x;
    __shared__ __align__(16) float QT[4096];   // Q-tile col-major, later P col-major
    __shared__ __align__(16) float BT[4096];   // nc col-major
    __shared__ __align__(16) float Ws[4096];   // W row-major
    const float* Qt = Qg + ((size_t)head * NSEQ + (size_t)tile * 64) * 64;
    loadT64(QT, Qt, t);
    loadT64(BT, ws + OFF_NC + (size_t)head * 4096, t);
    const float* Wg = ws + OFF_W + (size_t)head * 4096;
    for (int e = t; e < 1024; e += 256) {
        int m = e >> 4, k0 = (e & 15) << 2;
        *(float4*)(Ws + m * 64 + k0) = *(const float4*)(Wg + m * 64 + k0);
    }
    __syncthreads();
    int ti = t >> 4, tj = t & 15, i0 = ti << 2, j0 = tj << 2;
    float acc[4][4];
    mm64(QT, BT, acc, i0, j0);
    float sm[4];
#pragma unroll
    for (int r = 0; r < 4; r++) {
#pragma unroll
        for (int c = 0; c < 4; c++) acc[r][c] *= 0.125f;
        float m0 = fmaxf(fmaxf(acc[r][0], acc[r][1]), fmaxf(acc[r][2], acc[r][3]));
        m0 = fmaxf(m0, __shfl_xor(m0, 1)); m0 = fmaxf(m0, __shfl_xor(m0, 2));
        m0 = fmaxf(m0, __shfl_xor(m0, 4)); m0 = fmaxf(m0, __shfl_xor(m0, 8));
        float s = 0.f;
#pragma unroll
        for (int c = 0; c < 4; c++) { acc[r][c] = __expf(acc[r][c] - m0); s += acc[r][c]; }
        s += __shfl_xor(s, 1); s += __shfl_xor(s, 2);
        s += __shfl_xor(s, 4); s += __shfl_xor(s, 8);
        sm[r] = s;
    }
    __syncthreads();
    writeT64(QT, acc, i0, j0, 1.f);    // P col-major (unnormalized)
    __syncthreads();
    float x[4][4];
    mm64(QT, Ws, x, i0, j0);
    float* op = out + ((size_t)head * NSEQ + (size_t)tile * 64) * 64;
#pragma unroll
    for (int r = 0; r < 4; r++) {
        float4 v;
        v.x = x[r][0] / sm[r]; v.y = x[r][1] / sm[r];
        v.z = x[r][2] / sm[r]; v.w = x[r][3] / sm[r];
        *(float4*)(op + (i0 + r) * 64 + j0) = v;
    }
}

// ---------- launcher ----------
extern "C" void kernel_launch(void* const* d_in, const int* in_sizes, int n_in,
                              void* d_out, int out_size, void* d_ws, size_t ws_size,
                              hipStream_t stream) {
    const float* Q = (const float*)d_in[0];
    const float* K = (const float*)d_in[1];
    const float* V = (const float*)d_in[2];
    float* ws = (float*)d_ws;
    float* out = (float*)d_out;

    k_sums<<<4096, 256, 0, stream>>>(Q, K, ws);
    k_select<<<dim3(64, 2), 256, 0, stream>>>(Q, K, ws);
    k_u<<<64, 256, 0, stream>>>(ws);
    k_gmax<<<1, 64, 0, stream>>>(ws);
    k_rvp<<<dim3(64, 8), 256, 0, stream>>>(K, V, ws);
    k_nsinv<<<64, 256, 0, stream>>>(ws);
    k_comb<<<64, 256, 0, stream>>>(ws);
    k_final<<<dim3(64, 64), 256, 0, stream>>>(Q, ws, out);
}

// Round 2
// 236.690 us; speedup vs baseline: 1.3975x; 1.3975x over previous
//
#include <hip/hip_runtime.h>
#include <math.h>

// Problem constants: B=8, H=8 (BH=64 heads), N=4096, D=64, M=64, 6 NS iters.
#define NSEQ 4096

// workspace offsets (in float units). Total high-water ~16.0 MB.
// Lifetime-overlapped: WTH/WTL reuse SUMK region; U reuses SUMQ region.
#define OFF_SUMK 0u        // 262144  (k_sums -> k_select)
#define OFF_SUMQ 262144u   // 262144  (k_sums -> k_select)
#define OFF_WTH  0u        // 131072 floats = 262144 bf16 (k_comb -> k_final)
#define OFF_WTL  131072u
#define OFF_U    262144u   // 262144  (k_u -> k_nsinv)
#define OFF_NC   524288u   // f32 nc  (k_select -> k_u)
#define OFF_NR   786432u   // f32 nr  (k_select -> k_u)
#define OFF_VM   1048576u  // k_nsinv -> k_comb
#define OFF_NCH  1310720u  // bf16 arrays (k_select -> k_rvp/k_final)
#define OFF_NCL  1441792u
#define OFF_NRH  1572864u
#define OFF_NRL  1703936u
#define OFF_PMAX 1835008u  // 64*8*64
#define OFF_PSUM 1867776u
#define OFF_HMAX 1900544u
#define OFF_GMAX 1900608u
#define OFF_PRV  1900672u  // 64*8*64*64 = 2097152 -> end 3997824 floats

typedef unsigned short u16;
typedef short short8 __attribute__((ext_vector_type(8)));
typedef float f32x4 __attribute__((ext_vector_type(4)));

// ---------------- bf16 split helpers ----------------
__device__ __forceinline__ u16 f2bf(float x) {      // RNE f32->bf16 bits
    unsigned u = __float_as_uint(x);
    unsigned r = (u + 0x7FFFu + ((u >> 16) & 1u)) >> 16;
    return (u16)r;
}
__device__ __forceinline__ void splitbf(float x, u16& h, u16& l) {
    unsigned u = __float_as_uint(x);
    h = (u16)(u >> 16);                              // truncate -> exact residual
    float hf = __uint_as_float(u & 0xFFFF0000u);
    l = f2bf(x - hf);
}

// ---------------- swizzled LDS tile helpers (64x64 bf16, 128B rows) ----------------
__device__ __forceinline__ short8 ldfrag(const u16* base, int row, int k0) {
    int byte = (row << 7) + (k0 << 1);
    byte ^= (row & 7) << 4;
    return *(const short8*)((const char*)base + byte);
}
__device__ __forceinline__ void st4(u16* base, int row, int c0, ushort4 v) {
    int byte = (row << 7) + (c0 << 1);
    byte ^= (row & 7) << 4;
    *(ushort4*)((char*)base + byte) = v;
}
__device__ __forceinline__ void stb16(u16* base, int row, int c, u16 v) {
    int byte = (row << 7) + (c << 1);
    byte ^= (row & 7) << 4;
    *(u16*)((char*)base + byte) = v;
}

__device__ __forceinline__ f32x4 MFMA(short8 a, short8 b, f32x4 c) {
    return __builtin_amdgcn_mfma_f32_16x16x32_bf16(a, b, c, 0, 0, 0);
}

// stage 64x64 f32 global tile (row-major) -> hi/lo bf16 LDS, swizzled rows
__device__ __forceinline__ void stage64(const float* __restrict__ g, u16* Lh, u16* Ll,
                                        int t, float scale) {
#pragma unroll
    for (int i = 0; i < 4; i++) {
        int e = t + 256 * i;
        int row = e >> 4, c0 = (e & 15) << 2;
        float4 v = *(const float4*)(g + row * 64 + c0);
        float vv[4] = {v.x * scale, v.y * scale, v.z * scale, v.w * scale};
        ushort4 h, l;
        splitbf(vv[0], h.x, l.x); splitbf(vv[1], h.y, l.y);
        splitbf(vv[2], h.z, l.z); splitbf(vv[3], h.w, l.w);
        st4(Lh, row, c0, h); st4(Ll, row, c0, l);
    }
}

// stage 64x64 f32 global tile TRANSPOSED -> Lh/Ll[d][n] bf16, swizzled rows
__device__ __forceinline__ void stageT64(const float* __restrict__ g, u16* Lh, u16* Ll, int t) {
#pragma unroll
    for (int i = 0; i < 4; i++) {
        int e = t + 256 * i;
        int n = e >> 4, d0 = (e & 15) << 2;
        float4 v = *(const float4*)(g + n * 64 + d0);
        float vv[4] = {v.x, v.y, v.z, v.w};
#pragma unroll
        for (int k = 0; k < 4; k++) {
            u16 h, l; splitbf(vv[k], h, l);
            stb16(Lh, d0 + k, n, h); stb16(Ll, d0 + k, n, l);
        }
    }
}

// copy 64x64 bf16 (row-major in global) -> swizzled LDS
__device__ __forceinline__ void copy64bf(u16* dst, const u16* __restrict__ src, int t) {
#pragma unroll
    for (int i = 0; i < 4; i++) {
        int e = t + 256 * i;
        int row = e >> 4, c0 = (e & 15) << 2;
        ushort4 v = *(const ushort4*)(src + row * 64 + c0);
        st4(dst, row, c0, v);
    }
}

// ---------------- f32 64x64 VALU matmul helpers (small kernels) ----------------
__device__ __forceinline__ void loadT64(float* dst, const float* __restrict__ src, int t) {
    for (int e = t; e < 1024; e += 256) {
        int m = e >> 4, k0 = (e & 15) << 2;
        float4 v = *(const float4*)(src + m * 64 + k0);
        dst[(k0 + 0) * 64 + m] = v.x;
        dst[(k0 + 1) * 64 + m] = v.y;
        dst[(k0 + 2) * 64 + m] = v.z;
        dst[(k0 + 3) * 64 + m] = v.w;
    }
}
__device__ __forceinline__ void mm64add(const float* Acm, const float* Brm,
                                        float acc[4][4], int i0, int j0) {
#pragma unroll 8
    for (int k = 0; k < 64; k++) {
        float4 a = *(const float4*)(Acm + k * 64 + i0);
        float4 b = *(const float4*)(Brm + k * 64 + j0);
        acc[0][0] += a.x * b.x; acc[0][1] += a.x * b.y; acc[0][2] += a.x * b.z; acc[0][3] += a.x * b.w;
        acc[1][0] += a.y * b.x; acc[1][1] += a.y * b.y; acc[1][2] += a.y * b.z; acc[1][3] += a.y * b.w;
        acc[2][0] += a.z * b.x; acc[2][1] += a.z * b.y; acc[2][2] += a.z * b.z; acc[2][3] += a.z * b.w;
        acc[3][0] += a.w * b.x; acc[3][1] += a.w * b.y; acc[3][2] += a.w * b.z; acc[3][3] += a.w * b.w;
    }
}
__device__ __forceinline__ void mm64(const float* Acm, const float* Brm,
                                     float acc[4][4], int i0, int j0) {
#pragma unroll
    for (int r = 0; r < 4; r++)
#pragma unroll
        for (int c = 0; c < 4; c++) acc[r][c] = 0.f;
    mm64add(Acm, Brm, acc, i0, j0);
}
__device__ __forceinline__ void writeN64(float* dst, const float acc[4][4], int i0, int j0, float s) {
#pragma unroll
    for (int r = 0; r < 4; r++) {
        float4 v;
        v.x = s * acc[r][0]; v.y = s * acc[r][1]; v.z = s * acc[r][2]; v.w = s * acc[r][3];
        *(float4*)(dst + (i0 + r) * 64 + j0) = v;
    }
}
__device__ __forceinline__ void writeT64(float* dst, const float acc[4][4], int i0, int j0, float s) {
#pragma unroll
    for (int c = 0; c < 4; c++) {
        float4 v;
        v.x = s * acc[0][c]; v.y = s * acc[1][c]; v.z = s * acc[2][c]; v.w = s * acc[3][c];
        *(float4*)(dst + (j0 + c) * 64 + i0) = v;
    }
}

// ---------- kernel A: row sums of Q and K ----------
__global__ __launch_bounds__(256) void k_sums(const float* __restrict__ Qg,
                                              const float* __restrict__ Kg, float* ws) {
    size_t row = (size_t)blockIdx.x * 64 + (threadIdx.x >> 2);
    int q = threadIdx.x & 3;
    const float4* qp = (const float4*)(Qg + row * 64 + q * 16);
    const float4* kp = (const float4*)(Kg + row * 64 + q * 16);
    float s1 = 0.f, s2 = 0.f;
#pragma unroll
    for (int i = 0; i < 4; i++) { float4 v = qp[i]; s1 += (v.x + v.y) + (v.z + v.w); }
#pragma unroll
    for (int i = 0; i < 4; i++) { float4 v = kp[i]; s2 += (v.x + v.y) + (v.z + v.w); }
    s1 += __shfl_xor(s1, 1); s1 += __shfl_xor(s1, 2);
    s2 += __shfl_xor(s2, 1); s2 += __shfl_xor(s2, 2);
    if (q == 0) { ws[OFF_SUMQ + row] = s1; ws[OFF_SUMK + row] = s2; }
}

// ---------- kernel B: top-64 select (stable desc) + gather (f32 + bf16 hi/lo) ----------
__global__ __launch_bounds__(256) void k_select(const float* __restrict__ Qg,
                                                const float* __restrict__ Kg, float* ws) {
    int head = blockIdx.x, sel = blockIdx.y, t = threadIdx.x;
    __shared__ float sc[4096];
    __shared__ unsigned long long wred[4];
    __shared__ int idx_s[64];
    const float* scores = ws + (sel ? OFF_SUMQ : OFF_SUMK) + (size_t)head * 4096;
    for (int i = t; i < 4096; i += 256) sc[i] = scores[i];
    __syncthreads();
    int lane = t & 63, wid = t >> 6;
    for (int m = 0; m < 64; m++) {
        unsigned long long best = 0ull;
#pragma unroll
        for (int i = 0; i < 16; i++) {
            int e = i * 256 + t;
            unsigned uu = __float_as_uint(sc[e]);
            uu = (uu & 0x80000000u) ? ~uu : (uu | 0x80000000u);
            unsigned long long key = ((unsigned long long)uu << 32) |
                                     (unsigned)(0xFFFFFFFFu - (unsigned)e);
            if (key > best) best = key;
        }
#pragma unroll
        for (int s = 1; s < 64; s <<= 1) {
            unsigned long long o = __shfl_xor(best, s);
            if (o > best) best = o;
        }
        if (lane == 0) wred[wid] = best;
        __syncthreads();
        if (t == 0) {
            unsigned long long b = wred[0];
            if (wred[1] > b) b = wred[1];
            if (wred[2] > b) b = wred[2];
            if (wred[3] > b) b = wred[3];
            int widx = (int)(0xFFFFFFFFu - (unsigned)(b & 0xFFFFFFFFull));
            idx_s[m] = widx;
            sc[widx] = -INFINITY;
        }
        __syncthreads();
    }
    const float* src = sel ? Qg : Kg;
    float* dst = ws + (sel ? OFF_NR : OFF_NC) + (size_t)head * 4096;
    u16* dh = (u16*)(ws + (sel ? OFF_NRH : OFF_NCH)) + (size_t)head * 4096;
    u16* dl = (u16*)(ws + (sel ? OFF_NRL : OFF_NCL)) + (size_t)head * 4096;
    float scl = sel ? 0.125f : 1.0f;
    for (int e = t; e < 4096; e += 256) {
        int m = e >> 6, d = e & 63;
        float v = src[((size_t)head * NSEQ + (size_t)idx_s[m]) * 64 + d] * scl;
        dst[e] = v;
        u16 h, l; splitbf(v, h, l);
        dh[e] = h; dl[e] = l;
    }
}

// ---------- kernel C: u = softmax(nr @ nc^T) + per-head max colsum ----------
__global__ __launch_bounds__(256) void k_u(float* ws) {
    int head = blockIdx.x, t = threadIdx.x;
    __shared__ __align__(16) float A_s[4096];
    __shared__ __align__(16) float B_s[4096];
    __shared__ float colpart[1024];
    loadT64(A_s, ws + OFF_NR + (size_t)head * 4096, t);
    loadT64(B_s, ws + OFF_NC + (size_t)head * 4096, t);
    __syncthreads();
    int ti = t >> 4, tj = t & 15, i0 = ti << 2, j0 = tj << 2;
    float acc[4][4];
    mm64(A_s, B_s, acc, i0, j0);
#pragma unroll
    for (int r = 0; r < 4; r++) {
        float m0 = fmaxf(fmaxf(acc[r][0], acc[r][1]), fmaxf(acc[r][2], acc[r][3]));
        m0 = fmaxf(m0, __shfl_xor(m0, 1)); m0 = fmaxf(m0, __shfl_xor(m0, 2));
        m0 = fmaxf(m0, __shfl_xor(m0, 4)); m0 = fmaxf(m0, __shfl_xor(m0, 8));
        float s = 0.f;
#pragma unroll
        for (int c = 0; c < 4; c++) { acc[r][c] = __expf(acc[r][c] - m0); s += acc[r][c]; }
        s += __shfl_xor(s, 1); s += __shfl_xor(s, 2);
        s += __shfl_xor(s, 4); s += __shfl_xor(s, 8);
#pragma unroll
        for (int c = 0; c < 4; c++) acc[r][c] = acc[r][c] / s;
    }
    float* u = ws + OFF_U + (size_t)head * 4096;
#pragma unroll
    for (int r = 0; r < 4; r++) {
        float4 v; v.x = acc[r][0]; v.y = acc[r][1]; v.z = acc[r][2]; v.w = acc[r][3];
        *(float4*)(u + (i0 + r) * 64 + j0) = v;
    }
#pragma unroll
    for (int c = 0; c < 4; c++)
        colpart[ti * 64 + j0 + c] = acc[0][c] + acc[1][c] + acc[2][c] + acc[3][c];
    __syncthreads();
    if (t < 64) {
        float cs = 0.f;
#pragma unroll
        for (int g = 0; g < 16; g++) cs += colpart[g * 64 + t];
        float v = cs;
#pragma unroll
        for (int s = 1; s < 64; s <<= 1) v = fmaxf(v, __shfl_xor(v, s));
        if (t == 0) ws[OFF_HMAX + head] = v;
    }
}

// ---------- kernel D: global max ----------
__global__ void k_gmax(float* ws) {
    int t = threadIdx.x;
    float v = ws[OFF_HMAX + t];
#pragma unroll
    for (int s = 1; s < 64; s <<= 1) v = fmaxf(v, __shfl_xor(v, s));
    if (t == 0) ws[OFF_GMAX] = v;
}

// ---------- kernel E: Newton-Schulz iterative inverse (per head, f32) ----------
__global__ __launch_bounds__(256) void k_nsinv(float* ws) {
    int head = blockIdx.x, t = threadIdx.x;
    __shared__ __align__(16) float KmCm[4096];
    __shared__ __align__(16) float VmCm[4096];
    __shared__ __align__(16) float KVCm[4096];
    __shared__ __align__(16) float Sh[4096];
    const float* u = ws + OFF_U + (size_t)head * 4096;
    float g = ws[OFF_GMAX];
    for (int e = t; e < 1024; e += 256) {
        int i = e >> 4, k0 = (e & 15) << 2;
        float4 v = *(const float4*)(u + i * 64 + k0);
        KmCm[(k0 + 0) * 64 + i] = v.x; KmCm[(k0 + 1) * 64 + i] = v.y;
        KmCm[(k0 + 2) * 64 + i] = v.z; KmCm[(k0 + 3) * 64 + i] = v.w;
        Sh[(k0 + 0) * 64 + i] = v.x / g; Sh[(k0 + 1) * 64 + i] = v.y / g;
        Sh[(k0 + 2) * 64 + i] = v.z / g; Sh[(k0 + 3) * 64 + i] = v.w / g;
        float4 w; w.x = v.x / g; w.y = v.y / g; w.z = v.z / g; w.w = v.w / g;
        *(float4*)(VmCm + i * 64 + k0) = w;
    }
    __syncthreads();
    int ti = t >> 4, tj = t & 15, i0 = ti << 2, j0 = tj << 2;
    float acc[4][4], corr[4][4];
    for (int it = 0; it < 6; it++) {
        mm64(KmCm, Sh, acc, i0, j0);
        __syncthreads();
        writeN64(Sh, acc, i0, j0, 1.f);
        writeT64(KVCm, acc, i0, j0, 1.f);
        __syncthreads();
        mm64(KVCm, Sh, acc, i0, j0);
#pragma unroll
        for (int r = 0; r < 4; r++)
#pragma unroll
            for (int c = 0; c < 4; c++) corr[r][c] = Sh[(i0 + r) * 64 + j0 + c];
        __syncthreads();
#pragma unroll
        for (int r = 0; r < 4; r++)
#pragma unroll
            for (int c = 0; c < 4; c++) acc[r][c] = 7.f * corr[r][c] - acc[r][c];
        writeN64(Sh, acc, i0, j0, 1.f);
        __syncthreads();
        mm64(KVCm, Sh, acc, i0, j0);
#pragma unroll
        for (int r = 0; r < 4; r++)
#pragma unroll
            for (int c = 0; c < 4; c++) corr[r][c] = KVCm[(j0 + c) * 64 + i0 + r];
        __syncthreads();
#pragma unroll
        for (int r = 0; r < 4; r++)
#pragma unroll
            for (int c = 0; c < 4; c++) acc[r][c] = 15.f * corr[r][c] - acc[r][c];
        writeN64(Sh, acc, i0, j0, 1.f);
        __syncthreads();
        mm64(Sh, VmCm, acc, i0, j0);
#pragma unroll
        for (int r = 0; r < 4; r++)
#pragma unroll
            for (int c = 0; c < 4; c++) corr[r][c] = VmCm[(i0 + r) * 64 + j0 + c];
        __syncthreads();
#pragma unroll
        for (int r = 0; r < 4; r++)
#pragma unroll
            for (int c = 0; c < 4; c++) acc[r][c] = 0.25f * (13.f * corr[r][c] - acc[r][c]);
        writeN64(VmCm, acc, i0, j0, 1.f);
        writeT64(Sh, acc, i0, j0, 1.f);
        __syncthreads();
    }
    float* vm = ws + OFF_VM + (size_t)head * 4096;
    for (int e = t; e < 1024; e += 256) {
        int i = e >> 4, k0 = (e & 15) << 2;
        *(float4*)(vm + i * 64 + k0) = *(const float4*)(Sh + i * 64 + k0);
    }
}

// ---------- kernel F: flash softmax(nr@K^T)@V partials — MFMA split-bf16 ----------
__global__ __launch_bounds__(256) void k_rvp(const float* __restrict__ Kg,
                                             const float* __restrict__ Vg, float* ws) {
    int head = blockIdx.x, ch = blockIdx.y, t = threadIdx.x;
    __shared__ __align__(16) u16 NRh[4096], NRl[4096];
    __shared__ __align__(16) u16 Kh[4096], Kl[4096];
    __shared__ __align__(16) u16 Ph[4096], Pl[4096];
    __shared__ __align__(16) u16 Vth[4096], Vtl[4096];
    const u16* nrh = (const u16*)(ws + OFF_NRH) + (size_t)head * 4096;
    const u16* nrl = (const u16*)(ws + OFF_NRL) + (size_t)head * 4096;
    copy64bf(NRh, nrh, t);
    copy64bf(NRl, nrl, t);
    int w = t >> 6, lane = t & 63, lrow = lane & 15, lk = (lane >> 4) << 3;
    int mrow0 = 16 * w + ((lane >> 4) << 2);   // first of this lane's 4 output rows
    f32x4 rv[4];
#pragma unroll
    for (int dt = 0; dt < 4; dt++) rv[dt] = (f32x4){0.f, 0.f, 0.f, 0.f};
    float mrow[4] = {-INFINITY, -INFINITY, -INFINITY, -INFINITY};
    float srow[4] = {0.f, 0.f, 0.f, 0.f};
    const float* Kb = Kg + ((size_t)head * NSEQ + (size_t)ch * 512) * 64;
    const float* Vb = Vg + ((size_t)head * NSEQ + (size_t)ch * 512) * 64;
    for (int s8 = 0; s8 < 8; s8++) {
        __syncthreads();                       // prior reads of Kh/Vt/Ph complete
        stage64(Kb + s8 * 4096, Kh, Kl, t, 1.0f);
        stageT64(Vb + s8 * 4096, Vth, Vtl, t);
        __syncthreads();
        short8 a0h = ldfrag(NRh, 16 * w + lrow, lk);
        short8 a0l = ldfrag(NRl, 16 * w + lrow, lk);
        short8 a1h = ldfrag(NRh, 16 * w + lrow, 32 + lk);
        short8 a1l = ldfrag(NRl, 16 * w + lrow, 32 + lk);
        f32x4 sa[4];
#pragma unroll
        for (int nt = 0; nt < 4; nt++) {
            f32x4 acc = (f32x4){0.f, 0.f, 0.f, 0.f};
            short8 bh = ldfrag(Kh, 16 * nt + lrow, lk);
            short8 bl = ldfrag(Kl, 16 * nt + lrow, lk);
            acc = MFMA(a0h, bh, acc); acc = MFMA(a0l, bh, acc); acc = MFMA(a0h, bl, acc);
            bh = ldfrag(Kh, 16 * nt + lrow, 32 + lk);
            bl = ldfrag(Kl, 16 * nt + lrow, 32 + lk);
            acc = MFMA(a1h, bh, acc); acc = MFMA(a1l, bh, acc); acc = MFMA(a1h, bl, acc);
            sa[nt] = acc;
        }
        float scl[4];
#pragma unroll
        for (int j = 0; j < 4; j++) {
            float m0 = fmaxf(fmaxf(sa[0][j], sa[1][j]), fmaxf(sa[2][j], sa[3][j]));
            m0 = fmaxf(m0, __shfl_xor(m0, 1)); m0 = fmaxf(m0, __shfl_xor(m0, 2));
            m0 = fmaxf(m0, __shfl_xor(m0, 4)); m0 = fmaxf(m0, __shfl_xor(m0, 8));
            float mnew = fmaxf(mrow[j], m0);
            float sc = __expf(mrow[j] - mnew);
            float ps = 0.f;
#pragma unroll
            for (int nt = 0; nt < 4; nt++) {
                float p = __expf(sa[nt][j] - mnew);
                sa[nt][j] = p; ps += p;
            }
            ps += __shfl_xor(ps, 1); ps += __shfl_xor(ps, 2);
            ps += __shfl_xor(ps, 4); ps += __shfl_xor(ps, 8);
            srow[j] = srow[j] * sc + ps;
            mrow[j] = mnew;
            scl[j] = sc;
        }
#pragma unroll
        for (int dt = 0; dt < 4; dt++)
#pragma unroll
            for (int j = 0; j < 4; j++) rv[dt][j] *= scl[j];
#pragma unroll
        for (int nt = 0; nt < 4; nt++)
#pragma unroll
            for (int j = 0; j < 4; j++) {
                u16 h, l; splitbf(sa[nt][j], h, l);
                stb16(Ph, mrow0 + j, 16 * nt + lrow, h);
                stb16(Pl, mrow0 + j, 16 * nt + lrow, l);
            }
        __syncthreads();
        short8 p0h = ldfrag(Ph, 16 * w + lrow, lk);
        short8 p0l = ldfrag(Pl, 16 * w + lrow, lk);
        short8 p1h = ldfrag(Ph, 16 * w + lrow, 32 + lk);
        short8 p1l = ldfrag(Pl, 16 * w + lrow, 32 + lk);
#pragma unroll
        for (int dt = 0; dt < 4; dt++) {
            short8 bh = ldfrag(Vth, 16 * dt + lrow, lk);
            short8 bl = ldfrag(Vtl, 16 * dt + lrow, lk);
            rv[dt] = MFMA(p0h, bh, rv[dt]); rv[dt] = MFMA(p0l, bh, rv[dt]); rv[dt] = MFMA(p0h, bl, rv[dt]);
            bh = ldfrag(Vth, 16 * dt + lrow, 32 + lk);
            bl = ldfrag(Vtl, 16 * dt + lrow, 32 + lk);
            rv[dt] = MFMA(p1h, bh, rv[dt]); rv[dt] = MFMA(p1l, bh, rv[dt]); rv[dt] = MFMA(p1h, bl, rv[dt]);
        }
    }
    size_t pb = (size_t)(head * 8 + ch) * 64;
    if (lrow == 0) {
#pragma unroll
        for (int j = 0; j < 4; j++) {
            ws[OFF_PMAX + pb + mrow0 + j] = mrow[j];
            ws[OFF_PSUM + pb + mrow0 + j] = srow[j];
        }
    }
#pragma unroll
    for (int dt = 0; dt < 4; dt++)
#pragma unroll
        for (int j = 0; j < 4; j++)
            ws[OFF_PRV + (pb + mrow0 + j) * 64 + 16 * dt + lrow] = rv[dt][j];
}

// ---------- kernel G: combine partials -> RV; W = k2inv @ RV; write W^T bf16 ----------
__global__ __launch_bounds__(256) void k_comb(float* ws) {
    int head = blockIdx.x, t = threadIdx.x;
    __shared__ __align__(16) float A_s[4096];
    __shared__ __align__(16) float B_s[4096];
    loadT64(A_s, ws + OFF_VM + (size_t)head * 4096, t);
    int ti = t >> 4, tj = t & 15, i0 = ti << 2, j0 = tj << 2;
    const float* pm = ws + OFF_PMAX + (size_t)head * 512;
    const float* psv = ws + OFF_PSUM + (size_t)head * 512;
    const float* prv = ws + OFF_PRV + (size_t)head * 8 * 4096;
    float gm[4] = {-INFINITY, -INFINITY, -INFINITY, -INFINITY};
    for (int c8 = 0; c8 < 8; c8++)
#pragma unroll
        for (int r = 0; r < 4; r++) gm[r] = fmaxf(gm[r], pm[c8 * 64 + i0 + r]);
    float stot[4] = {0.f, 0.f, 0.f, 0.f};
    float racc[4][4];
#pragma unroll
    for (int r = 0; r < 4; r++)
#pragma unroll
        for (int c = 0; c < 4; c++) racc[r][c] = 0.f;
    for (int c8 = 0; c8 < 8; c8++) {
#pragma unroll
        for (int r = 0; r < 4; r++) {
            float w = __expf(pm[c8 * 64 + i0 + r] - gm[r]);
            stot[r] += w * psv[c8 * 64 + i0 + r];
            float4 v = *(const float4*)(prv + (size_t)(c8 * 64 + i0 + r) * 64 + j0);
            racc[r][0] += w * v.x; racc[r][1] += w * v.y;
            racc[r][2] += w * v.z; racc[r][3] += w * v.w;
        }
    }
#pragma unroll
    for (int r = 0; r < 4; r++)
#pragma unroll
        for (int c = 0; c < 4; c++) racc[r][c] /= stot[r];
    writeN64(B_s, racc, i0, j0, 1.f);
    __syncthreads();
    float acc[4][4];
    mm64(A_s, B_s, acc, i0, j0);
    u16* wth = (u16*)(ws + OFF_WTH) + (size_t)head * 4096;
    u16* wtl = (u16*)(ws + OFF_WTL) + (size_t)head * 4096;
#pragma unroll
    for (int r = 0; r < 4; r++)
#pragma unroll
        for (int c = 0; c < 4; c++) {
            u16 h, l; splitbf(acc[r][c], h, l);
            wth[(j0 + c) * 64 + (i0 + r)] = h;   // W^T[d][n]
            wtl[(j0 + c) * 64 + (i0 + r)] = l;
        }
}

// ---------- kernel H: X = softmax(Q@nc^T/8) @ W — MFMA split-bf16 ----------
__global__ __launch_bounds__(256) void k_final(const float* __restrict__ Qg, float* ws,
                                               float* __restrict__ out) {
    int tile = blockIdx.x, head = blockIdx.y, t = threadIdx.x;
    __shared__ __align__(16) u16 Ah[4096], Al[4096];   // Q then P
    __shared__ __align__(16) u16 Bh[4096], Bl[4096];   // nc then W^T
    __shared__ __align__(16) float C[64 * 68];
    const float* Qt = Qg + ((size_t)head * NSEQ + (size_t)tile * 64) * 64;
    stage64(Qt, Ah, Al, t, 0.125f);
    copy64bf(Bh, (const u16*)(ws + OFF_NCH) + (size_t)head * 4096, t);
    copy64bf(Bl, (const u16*)(ws + OFF_NCL) + (size_t)head * 4096, t);
    __syncthreads();
    int w = t >> 6, lane = t & 63, lrow = lane & 15, lk = (lane >> 4) << 3;
    int mrow0 = 16 * w + ((lane >> 4) << 2);
    short8 a0h = ldfrag(Ah, 16 * w + lrow, lk);
    short8 a0l = ldfrag(Al, 16 * w + lrow, lk);
    short8 a1h = ldfrag(Ah, 16 * w + lrow, 32 + lk);
    short8 a1l = ldfrag(Al, 16 * w + lrow, 32 + lk);
    f32x4 sa[4];
#pragma unroll
    for (int nt = 0; nt < 4; nt++) {
        f32x4 acc = (f32x4){0.f, 0.f, 0.f, 0.f};
        short8 bh = ldfrag(Bh, 16 * nt + lrow, lk);
        short8 bl = ldfrag(Bl, 16 * nt + lrow, lk);
        acc = MFMA(a0h, bh, acc); acc = MFMA(a0l, bh, acc); acc = MFMA(a0h, bl, acc);
        bh = ldfrag(Bh, 16 * nt + lrow, 32 + lk);
        bl = ldfrag(Bl, 16 * nt + lrow, 32 + lk);
        acc = MFMA(a1h, bh, acc); acc = MFMA(a1l, bh, acc); acc = MFMA(a1h, bl, acc);
        sa[nt] = acc;
    }
#pragma unroll
    for (int j = 0; j < 4; j++) {
        float m0 = fmaxf(fmaxf(sa[0][j], sa[1][j]), fmaxf(sa[2][j], sa[3][j]));
        m0 = fmaxf(m0, __shfl_xor(m0, 1)); m0 = fmaxf(m0, __shfl_xor(m0, 2));
        m0 = fmaxf(m0, __shfl_xor(m0, 4)); m0 = fmaxf(m0, __shfl_xor(m0, 8));
        float ps = 0.f;
#pragma unroll
        for (int nt = 0; nt < 4; nt++) {
            float p = __expf(sa[nt][j] - m0);
            sa[nt][j] = p; ps += p;
        }
        ps += __shfl_xor(ps, 1); ps += __shfl_xor(ps, 2);
        ps += __shfl_xor(ps, 4); ps += __shfl_xor(ps, 8);
        float inv = 1.f / ps;
#pragma unroll
        for (int nt = 0; nt < 4; nt++) sa[nt][j] *= inv;
    }
    __syncthreads();                           // done reading Q/nc from LDS
#pragma unroll
    for (int nt = 0; nt < 4; nt++)
#pragma unroll
        for (int j = 0; j < 4; j++) {
            u16 h, l; splitbf(sa[nt][j], h, l);
            stb16(Ah, mrow0 + j, 16 * nt + lrow, h);
            stb16(Al, mrow0 + j, 16 * nt + lrow, l);
        }
    copy64bf(Bh, (const u16*)(ws + OFF_WTH) + (size_t)head * 4096, t);
    copy64bf(Bl, (const u16*)(ws + OFF_WTL) + (size_t)head * 4096, t);
    __syncthreads();
    short8 p0h = ldfrag(Ah, 16 * w + lrow, lk);
    short8 p0l = ldfrag(Al, 16 * w + lrow, lk);
    short8 p1h = ldfrag(Ah, 16 * w + lrow, 32 + lk);
    short8 p1l = ldfrag(Al, 16 * w + lrow, 32 + lk);
#pragma unroll
    for (int dt = 0; dt < 4; dt++) {
        f32x4 x = (f32x4){0.f, 0.f, 0.f, 0.f};
        short8 bh = ldfrag(Bh, 16 * dt + lrow, lk);
        short8 bl = ldfrag(Bl, 16 * dt + lrow, lk);
        x = MFMA(p0h, bh, x); x = MFMA(p0l, bh, x); x = MFMA(p0h, bl, x);
        bh = ldfrag(Bh, 16 * dt + lrow, 32 + lk);
        bl = ldfrag(Bl, 16 * dt + lrow, 32 + lk);
        x = MFMA(p1h, bh, x); x = MFMA(p1l, bh, x); x = MFMA(p1h, bl, x);
#pragma unroll
        for (int j = 0; j < 4; j++) C[(mrow0 + j) * 68 + 16 * dt + lrow] = x[j];
    }
    __syncthreads();
    float* op = out + ((size_t)head * NSEQ + (size_t)tile * 64) * 64;
#pragma unroll
    for (int i = 0; i < 4; i++) {
        int e = t + 256 * i;
        int row = e >> 4, c0 = (e & 15) << 2;
        *(float4*)(op + row * 64 + c0) = *(const float4*)(C + row * 68 + c0);
    }
}

// ---------- launcher ----------
extern "C" void kernel_launch(void* const* d_in, const int* in_sizes, int n_in,
                              void* d_out, int out_size, void* d_ws, size_t ws_size,
                              hipStream_t stream) {
    const float* Q = (const float*)d_in[0];
    const float* K = (const float*)d_in[1];
    const float* V = (const float*)d_in[2];
    float* ws = (float*)d_ws;
    float* out = (float*)d_out;

    k_sums<<<4096, 256, 0, stream>>>(Q, K, ws);
    k_select<<<dim3(64, 2), 256, 0, stream>>>(Q, K, ws);
    k_u<<<64, 256, 0, stream>>>(ws);
    k_gmax<<<1, 64, 0, stream>>>(ws);
    k_rvp<<<dim3(64, 8), 256, 0, stream>>>(K, V, ws);
    k_nsinv<<<64, 256, 0, stream>>>(ws);
    k_comb<<<64, 256, 0, stream>>>(ws);
    k_final<<<dim3(64, 64), 256, 0, stream>>>(Q, ws, out);
}

// Round 3
// 197.557 us; speedup vs baseline: 1.6744x; 1.1981x over previous
//
#include <hip/hip_runtime.h>
#include <math.h>

// Problem constants: B=8, H=8 (BH=64 heads), N=4096, D=64, M=64, 6 NS iters.
#define NSEQ 4096

// workspace offsets (in float units). Total high-water ~16.0 MB.
#define OFF_SUMK 0u        // 262144  (k_sums -> k_select)
#define OFF_SUMQ 262144u   // 262144  (k_sums -> k_select)
#define OFF_WTH  0u        // bf16 W^T hi (k_comb -> k_final)
#define OFF_WTL  131072u
#define OFF_U    262144u   // (k_u -> k_nsinv)
#define OFF_NC   524288u   // f32 nc  (k_select -> k_u)
#define OFF_NR   786432u   // f32 nr  (k_select -> k_u)
#define OFF_VM   1048576u  // k_nsinv -> k_comb
#define OFF_NCH  1310720u  // bf16 arrays (k_select -> k_rvp/k_final)
#define OFF_NCL  1441792u
#define OFF_NRH  1572864u
#define OFF_NRL  1703936u
#define OFF_PMAX 1835008u  // 64*8*64
#define OFF_PSUM 1867776u
#define OFF_HMAX 1900544u
#define OFF_PRV  1900672u  // 64*8*64*64 = 2097152 -> end 3997824 floats

typedef unsigned short u16;
typedef short short8 __attribute__((ext_vector_type(8)));
typedef float f32x4 __attribute__((ext_vector_type(4)));

// ---------------- bf16 split helpers ----------------
__device__ __forceinline__ u16 f2bf(float x) {      // RNE f32->bf16 bits
    unsigned u = __float_as_uint(x);
    unsigned r = (u + 0x7FFFu + ((u >> 16) & 1u)) >> 16;
    return (u16)r;
}
__device__ __forceinline__ void splitbf(float x, u16& h, u16& l) {
    unsigned u = __float_as_uint(x);
    h = (u16)(u >> 16);                              // truncate -> exact residual
    float hf = __uint_as_float(u & 0xFFFF0000u);
    l = f2bf(x - hf);
}

// ---------------- swizzled LDS tile helpers (64x64 bf16, 128B rows) ----------------
__device__ __forceinline__ short8 ldfrag(const u16* base, int row, int k0) {
    int byte = (row << 7) + (k0 << 1);
    byte ^= (row & 7) << 4;
    return *(const short8*)((const char*)base + byte);
}
__device__ __forceinline__ void st4(u16* base, int row, int c0, ushort4 v) {
    int byte = (row << 7) + (c0 << 1);
    byte ^= (row & 7) << 4;
    *(ushort4*)((char*)base + byte) = v;
}
__device__ __forceinline__ void stb16(u16* base, int row, int c, u16 v) {
    int byte = (row << 7) + (c << 1);
    byte ^= (row & 7) << 4;
    *(u16*)((char*)base + byte) = v;
}

__device__ __forceinline__ f32x4 MFMA(short8 a, short8 b, f32x4 c) {
    return __builtin_amdgcn_mfma_f32_16x16x32_bf16(a, b, c, 0, 0, 0);
}

// C[m][n] = sum_k A[m][k]*B_arr[n][k], split-bf16 3-product.
// Output: cv[nt][j] = C[mrow0+j][16*nt+lrow]
__device__ __forceinline__ void mfma_mm(const u16* AH, const u16* AL,
                                        const u16* BH, const u16* BL,
                                        f32x4 cv[4], int w, int lrow, int lk) {
    short8 a0h = ldfrag(AH, 16 * w + lrow, lk);
    short8 a0l = ldfrag(AL, 16 * w + lrow, lk);
    short8 a1h = ldfrag(AH, 16 * w + lrow, 32 + lk);
    short8 a1l = ldfrag(AL, 16 * w + lrow, 32 + lk);
#pragma unroll
    for (int nt = 0; nt < 4; nt++) {
        f32x4 acc = (f32x4){0.f, 0.f, 0.f, 0.f};
        short8 bh = ldfrag(BH, 16 * nt + lrow, lk);
        short8 bl = ldfrag(BL, 16 * nt + lrow, lk);
        acc = MFMA(a0h, bh, acc); acc = MFMA(a0l, bh, acc); acc = MFMA(a0h, bl, acc);
        bh = ldfrag(BH, 16 * nt + lrow, 32 + lk);
        bl = ldfrag(BL, 16 * nt + lrow, 32 + lk);
        acc = MFMA(a1h, bh, acc); acc = MFMA(a1l, bh, acc); acc = MFMA(a1h, bl, acc);
        cv[nt] = acc;
    }
}

// stage 64x64 f32 global tile (row-major) -> hi/lo bf16 LDS, swizzled rows
__device__ __forceinline__ void stage64(const float* __restrict__ g, u16* Lh, u16* Ll,
                                        int t, float scale) {
#pragma unroll
    for (int i = 0; i < 4; i++) {
        int e = t + 256 * i;
        int row = e >> 4, c0 = (e & 15) << 2;
        float4 v = *(const float4*)(g + row * 64 + c0);
        float vv[4] = {v.x * scale, v.y * scale, v.z * scale, v.w * scale};
        ushort4 h, l;
        splitbf(vv[0], h.x, l.x); splitbf(vv[1], h.y, l.y);
        splitbf(vv[2], h.z, l.z); splitbf(vv[3], h.w, l.w);
        st4(Lh, row, c0, h); st4(Ll, row, c0, l);
    }
}

// stage 64x64 f32 global tile TRANSPOSED -> Lh/Ll[d][n] bf16, swizzled rows
__device__ __forceinline__ void stageT64(const float* __restrict__ g, u16* Lh, u16* Ll, int t) {
#pragma unroll
    for (int i = 0; i < 4; i++) {
        int e = t + 256 * i;
        int n = e >> 4, d0 = (e & 15) << 2;
        float4 v = *(const float4*)(g + n * 64 + d0);
        float vv[4] = {v.x, v.y, v.z, v.w};
#pragma unroll
        for (int k = 0; k < 4; k++) {
            u16 h, l; splitbf(vv[k], h, l);
            stb16(Lh, d0 + k, n, h); stb16(Ll, d0 + k, n, l);
        }
    }
}

// copy 64x64 bf16 (row-major in global) -> swizzled LDS
__device__ __forceinline__ void copy64bf(u16* dst, const u16* __restrict__ src, int t) {
#pragma unroll
    for (int i = 0; i < 4; i++) {
        int e = t + 256 * i;
        int row = e >> 4, c0 = (e & 15) << 2;
        ushort4 v = *(const ushort4*)(src + row * 64 + c0);
        st4(dst, row, c0, v);
    }
}

// ---------------- f32 64x64 VALU matmul helpers (small kernels) ----------------
__device__ __forceinline__ void loadT64(float* dst, const float* __restrict__ src, int t) {
    for (int e = t; e < 1024; e += 256) {
        int m = e >> 4, k0 = (e & 15) << 2;
        float4 v = *(const float4*)(src + m * 64 + k0);
        dst[(k0 + 0) * 64 + m] = v.x;
        dst[(k0 + 1) * 64 + m] = v.y;
        dst[(k0 + 2) * 64 + m] = v.z;
        dst[(k0 + 3) * 64 + m] = v.w;
    }
}
__device__ __forceinline__ void mm64add(const float* Acm, const float* Brm,
                                        float acc[4][4], int i0, int j0) {
#pragma unroll 8
    for (int k = 0; k < 64; k++) {
        float4 a = *(const float4*)(Acm + k * 64 + i0);
        float4 b = *(const float4*)(Brm + k * 64 + j0);
        acc[0][0] += a.x * b.x; acc[0][1] += a.x * b.y; acc[0][2] += a.x * b.z; acc[0][3] += a.x * b.w;
        acc[1][0] += a.y * b.x; acc[1][1] += a.y * b.y; acc[1][2] += a.y * b.z; acc[1][3] += a.y * b.w;
        acc[2][0] += a.z * b.x; acc[2][1] += a.z * b.y; acc[2][2] += a.z * b.z; acc[2][3] += a.z * b.w;
        acc[3][0] += a.w * b.x; acc[3][1] += a.w * b.y; acc[3][2] += a.w * b.z; acc[3][3] += a.w * b.w;
    }
}
__device__ __forceinline__ void mm64(const float* Acm, const float* Brm,
                                     float acc[4][4], int i0, int j0) {
#pragma unroll
    for (int r = 0; r < 4; r++)
#pragma unroll
        for (int c = 0; c < 4; c++) acc[r][c] = 0.f;
    mm64add(Acm, Brm, acc, i0, j0);
}
__device__ __forceinline__ void writeN64(float* dst, const float acc[4][4], int i0, int j0, float s) {
#pragma unroll
    for (int r = 0; r < 4; r++) {
        float4 v;
        v.x = s * acc[r][0]; v.y = s * acc[r][1]; v.z = s * acc[r][2]; v.w = s * acc[r][3];
        *(float4*)(dst + (i0 + r) * 64 + j0) = v;
    }
}

// ---------- kernel A: row sums of Q and K ----------
__global__ __launch_bounds__(256) void k_sums(const float* __restrict__ Qg,
                                              const float* __restrict__ Kg, float* ws) {
    size_t row = (size_t)blockIdx.x * 64 + (threadIdx.x >> 2);
    int q = threadIdx.x & 3;
    const float4* qp = (const float4*)(Qg + row * 64 + q * 16);
    const float4* kp = (const float4*)(Kg + row * 64 + q * 16);
    float s1 = 0.f, s2 = 0.f;
#pragma unroll
    for (int i = 0; i < 4; i++) { float4 v = qp[i]; s1 += (v.x + v.y) + (v.z + v.w); }
#pragma unroll
    for (int i = 0; i < 4; i++) { float4 v = kp[i]; s2 += (v.x + v.y) + (v.z + v.w); }
    s1 += __shfl_xor(s1, 1); s1 += __shfl_xor(s1, 2);
    s2 += __shfl_xor(s2, 1); s2 += __shfl_xor(s2, 2);
    if (q == 0) { ws[OFF_SUMQ + row] = s1; ws[OFF_SUMK + row] = s2; }
}

// ---------- kernel B: top-64 select (stable desc) + gather (f32 + bf16 hi/lo) ----------
__global__ __launch_bounds__(256) void k_select(const float* __restrict__ Qg,
                                                const float* __restrict__ Kg, float* ws) {
    int head = blockIdx.x, sel = blockIdx.y, t = threadIdx.x;
    __shared__ float sc[4096];
    __shared__ unsigned long long wred[4];
    __shared__ int idx_s[64];
    const float* scores = ws + (sel ? OFF_SUMQ : OFF_SUMK) + (size_t)head * 4096;
    for (int i = t; i < 4096; i += 256) sc[i] = scores[i];
    __syncthreads();
    int lane = t & 63, wid = t >> 6;
    for (int m = 0; m < 64; m++) {
        unsigned long long best = 0ull;
#pragma unroll
        for (int i = 0; i < 16; i++) {
            int e = i * 256 + t;
            unsigned uu = __float_as_uint(sc[e]);
            uu = (uu & 0x80000000u) ? ~uu : (uu | 0x80000000u);
            unsigned long long key = ((unsigned long long)uu << 32) |
                                     (unsigned)(0xFFFFFFFFu - (unsigned)e);
            if (key > best) best = key;
        }
#pragma unroll
        for (int s = 1; s < 64; s <<= 1) {
            unsigned long long o = __shfl_xor(best, s);
            if (o > best) best = o;
        }
        if (lane == 0) wred[wid] = best;
        __syncthreads();
        if (t == 0) {
            unsigned long long b = wred[0];
            if (wred[1] > b) b = wred[1];
            if (wred[2] > b) b = wred[2];
            if (wred[3] > b) b = wred[3];
            int widx = (int)(0xFFFFFFFFu - (unsigned)(b & 0xFFFFFFFFull));
            idx_s[m] = widx;
            sc[widx] = -INFINITY;
        }
        __syncthreads();
    }
    const float* src = sel ? Qg : Kg;
    float* dst = ws + (sel ? OFF_NR : OFF_NC) + (size_t)head * 4096;
    u16* dh = (u16*)(ws + (sel ? OFF_NRH : OFF_NCH)) + (size_t)head * 4096;
    u16* dl = (u16*)(ws + (sel ? OFF_NRL : OFF_NCL)) + (size_t)head * 4096;
    float scl = sel ? 0.125f : 1.0f;
    for (int e = t; e < 4096; e += 256) {
        int m = e >> 6, d = e & 63;
        float v = src[((size_t)head * NSEQ + (size_t)idx_s[m]) * 64 + d] * scl;
        dst[e] = v;
        u16 h, l; splitbf(v, h, l);
        dh[e] = h; dl[e] = l;
    }
}

// ---------- kernel C: u = softmax(nr @ nc^T) + per-head max colsum ----------
__global__ __launch_bounds__(256) void k_u(float* ws) {
    int head = blockIdx.x, t = threadIdx.x;
    __shared__ __align__(16) float A_s[4096];
    __shared__ __align__(16) float B_s[4096];
    __shared__ float colpart[1024];
    loadT64(A_s, ws + OFF_NR + (size_t)head * 4096, t);
    loadT64(B_s, ws + OFF_NC + (size_t)head * 4096, t);
    __syncthreads();
    int ti = t >> 4, tj = t & 15, i0 = ti << 2, j0 = tj << 2;
    float acc[4][4];
    mm64(A_s, B_s, acc, i0, j0);
#pragma unroll
    for (int r = 0; r < 4; r++) {
        float m0 = fmaxf(fmaxf(acc[r][0], acc[r][1]), fmaxf(acc[r][2], acc[r][3]));
        m0 = fmaxf(m0, __shfl_xor(m0, 1)); m0 = fmaxf(m0, __shfl_xor(m0, 2));
        m0 = fmaxf(m0, __shfl_xor(m0, 4)); m0 = fmaxf(m0, __shfl_xor(m0, 8));
        float s = 0.f;
#pragma unroll
        for (int c = 0; c < 4; c++) { acc[r][c] = __expf(acc[r][c] - m0); s += acc[r][c]; }
        s += __shfl_xor(s, 1); s += __shfl_xor(s, 2);
        s += __shfl_xor(s, 4); s += __shfl_xor(s, 8);
#pragma unroll
        for (int c = 0; c < 4; c++) acc[r][c] = acc[r][c] / s;
    }
    float* u = ws + OFF_U + (size_t)head * 4096;
#pragma unroll
    for (int r = 0; r < 4; r++) {
        float4 v; v.x = acc[r][0]; v.y = acc[r][1]; v.z = acc[r][2]; v.w = acc[r][3];
        *(float4*)(u + (i0 + r) * 64 + j0) = v;
    }
#pragma unroll
    for (int c = 0; c < 4; c++)
        colpart[ti * 64 + j0 + c] = acc[0][c] + acc[1][c] + acc[2][c] + acc[3][c];
    __syncthreads();
    if (t < 64) {
        float cs = 0.f;
#pragma unroll
        for (int g = 0; g < 16; g++) cs += colpart[g * 64 + t];
        float v = cs;
#pragma unroll
        for (int s = 1; s < 64; s <<= 1) v = fmaxf(v, __shfl_xor(v, s));
        if (t == 0) ws[OFF_HMAX + head] = v;
    }
}

// ---------- kernel E: Newton-Schulz inverse via MFMA split-bf16 ----------
__global__ __launch_bounds__(256) void k_nsinv(float* ws) {
    int head = blockIdx.x, t = threadIdx.x;
    __shared__ __align__(16) u16 KmH[4096], KmL[4096];   // Km, N layout
    __shared__ __align__(16) u16 VmNH[4096], VmNL[4096]; // Vm, N layout
    __shared__ __align__(16) u16 VmTH[4096], VmTL[4096]; // Vm^T layout (B-operand)
    __shared__ __align__(16) u16 KVH[4096], KVL[4096];   // KV, N layout
    __shared__ __align__(16) u16 BtH[4096], BtL[4096];   // rotating B-operand (T layout)
    __shared__ __align__(16) float Vmf[4096];            // Vm f32 row-major (unswizzled)

    int w = t >> 6, lane = t & 63, lrow = lane & 15, lk = (lane >> 4) << 3;
    int mrow0 = 16 * w + ((lane >> 4) << 2);

    // global max over per-head colsum maxima (fold of old k_gmax)
    float g = ws[OFF_HMAX + lane];
#pragma unroll
    for (int s = 1; s < 64; s <<= 1) g = fmaxf(g, __shfl_xor(g, s));
    float ginv = 1.0f / g;

    // init: Km = u;  Vm = u^T/g  (VmT layout == u/g row-major)
    const float* u = ws + OFF_U + (size_t)head * 4096;
#pragma unroll
    for (int i = 0; i < 4; i++) {
        int e = t + 256 * i;
        int row = e >> 4, c0 = (e & 15) << 2;
        float4 v = *(const float4*)(u + row * 64 + c0);
        float vv[4] = {v.x, v.y, v.z, v.w};
        ushort4 h4, l4;
        splitbf(vv[0], h4.x, l4.x); splitbf(vv[1], h4.y, l4.y);
        splitbf(vv[2], h4.z, l4.z); splitbf(vv[3], h4.w, l4.w);
        st4(KmH, row, c0, h4); st4(KmL, row, c0, l4);
        float sv[4] = {vv[0] * ginv, vv[1] * ginv, vv[2] * ginv, vv[3] * ginv};
        splitbf(sv[0], h4.x, l4.x); splitbf(sv[1], h4.y, l4.y);
        splitbf(sv[2], h4.z, l4.z); splitbf(sv[3], h4.w, l4.w);
        st4(VmTH, row, c0, h4); st4(VmTL, row, c0, l4);
#pragma unroll
        for (int k = 0; k < 4; k++) {
            u16 h, l; splitbf(sv[k], h, l);
            stb16(VmNH, c0 + k, row, h); stb16(VmNL, c0 + k, row, l);
            Vmf[(c0 + k) * 64 + row] = sv[k];
        }
    }
    __syncthreads();

    f32x4 cv[4];
    for (int it = 0; it < 6; it++) {
        // s1: KV = Km @ Vm   (A=KmN, B=VmT); store KVN and Bt=(7I-KV)^T (disjoint arrays)
        mfma_mm(KmH, KmL, VmTH, VmTL, cv, w, lrow, lk);
#pragma unroll
        for (int nt = 0; nt < 4; nt++)
#pragma unroll
            for (int j = 0; j < 4; j++) {
                int m = mrow0 + j, n = 16 * nt + lrow;
                float v = cv[nt][j];
                u16 h, l; splitbf(v, h, l);
                stb16(KVH, m, n, h); stb16(KVL, m, n, l);
                float b = ((m == n) ? 7.f : 0.f) - v;
                splitbf(b, h, l);
                stb16(BtH, n, m, h); stb16(BtL, n, m, l);
            }
        __syncthreads();
        // s2: M2 = KV @ M1;  Bt' = (15I - M2)^T
        mfma_mm(KVH, KVL, BtH, BtL, cv, w, lrow, lk);
        __syncthreads();
#pragma unroll
        for (int nt = 0; nt < 4; nt++)
#pragma unroll
            for (int j = 0; j < 4; j++) {
                int m = mrow0 + j, n = 16 * nt + lrow;
                float b = ((m == n) ? 15.f : 0.f) - cv[nt][j];
                u16 h, l; splitbf(b, h, l);
                stb16(BtH, n, m, h); stb16(BtL, n, m, l);
            }
        __syncthreads();
        // s3: M4 = KV @ M3;  Bt'' = (13I - M4)^T
        mfma_mm(KVH, KVL, BtH, BtL, cv, w, lrow, lk);
        __syncthreads();
#pragma unroll
        for (int nt = 0; nt < 4; nt++)
#pragma unroll
            for (int j = 0; j < 4; j++) {
                int m = mrow0 + j, n = 16 * nt + lrow;
                float b = ((m == n) ? 13.f : 0.f) - cv[nt][j];
                u16 h, l; splitbf(b, h, l);
                stb16(BtH, n, m, h); stb16(BtL, n, m, l);
            }
        __syncthreads();
        // s4: Vm' = 0.25 * Vm @ M5   (A=VmN, B=Bt)
        mfma_mm(VmNH, VmNL, BtH, BtL, cv, w, lrow, lk);
        __syncthreads();
#pragma unroll
        for (int nt = 0; nt < 4; nt++)
#pragma unroll
            for (int j = 0; j < 4; j++) {
                int m = mrow0 + j, n = 16 * nt + lrow;
                float v = 0.25f * cv[nt][j];
                u16 h, l; splitbf(v, h, l);
                stb16(VmNH, m, n, h); stb16(VmNL, m, n, l);
                stb16(VmTH, n, m, h); stb16(VmTL, n, m, l);
                Vmf[m * 64 + n] = v;
            }
        __syncthreads();
    }

    float* vm = ws + OFF_VM + (size_t)head * 4096;
#pragma unroll
    for (int i = 0; i < 4; i++) {
        int e = t + 256 * i;
        int row = e >> 4, c0 = (e & 15) << 2;
        *(float4*)(vm + row * 64 + c0) = *(const float4*)(Vmf + row * 64 + c0);
    }
}

// ---------- kernel F: flash softmax(nr@K^T)@V partials — MFMA split-bf16 ----------
__global__ __launch_bounds__(256) void k_rvp(const float* __restrict__ Kg,
                                             const float* __restrict__ Vg, float* ws) {
    int head = blockIdx.x, ch = blockIdx.y, t = threadIdx.x;
    __shared__ __align__(16) u16 NRh[4096], NRl[4096];
    __shared__ __align__(16) u16 Kh[4096], Kl[4096];
    __shared__ __align__(16) u16 Ph[4096], Pl[4096];
    __shared__ __align__(16) u16 Vth[4096], Vtl[4096];
    const u16* nrh = (const u16*)(ws + OFF_NRH) + (size_t)head * 4096;
    const u16* nrl = (const u16*)(ws + OFF_NRL) + (size_t)head * 4096;
    copy64bf(NRh, nrh, t);
    copy64bf(NRl, nrl, t);
    int w = t >> 6, lane = t & 63, lrow = lane & 15, lk = (lane >> 4) << 3;
    int mrow0 = 16 * w + ((lane >> 4) << 2);
    __syncthreads();
    // loop-invariant A fragments (nr)
    short8 a0h = ldfrag(NRh, 16 * w + lrow, lk);
    short8 a0l = ldfrag(NRl, 16 * w + lrow, lk);
    short8 a1h = ldfrag(NRh, 16 * w + lrow, 32 + lk);
    short8 a1l = ldfrag(NRl, 16 * w + lrow, 32 + lk);
    f32x4 rv[4];
#pragma unroll
    for (int dt = 0; dt < 4; dt++) rv[dt] = (f32x4){0.f, 0.f, 0.f, 0.f};
    float mrow[4] = {-INFINITY, -INFINITY, -INFINITY, -INFINITY};
    float srow[4] = {0.f, 0.f, 0.f, 0.f};
    const float* Kb = Kg + ((size_t)head * NSEQ + (size_t)ch * 512) * 64;
    const float* Vb = Vg + ((size_t)head * NSEQ + (size_t)ch * 512) * 64;
    for (int s8 = 0; s8 < 8; s8++) {
        __syncthreads();                       // prior reads of Kh/Vt/Ph complete
        stage64(Kb + s8 * 4096, Kh, Kl, t, 1.0f);
        stageT64(Vb + s8 * 4096, Vth, Vtl, t);
        __syncthreads();
        f32x4 sa[4];
#pragma unroll
        for (int nt = 0; nt < 4; nt++) {
            f32x4 acc = (f32x4){0.f, 0.f, 0.f, 0.f};
            short8 bh = ldfrag(Kh, 16 * nt + lrow, lk);
            short8 bl = ldfrag(Kl, 16 * nt + lrow, lk);
            acc = MFMA(a0h, bh, acc); acc = MFMA(a0l, bh, acc); acc = MFMA(a0h, bl, acc);
            bh = ldfrag(Kh, 16 * nt + lrow, 32 + lk);
            bl = ldfrag(Kl, 16 * nt + lrow, 32 + lk);
            acc = MFMA(a1h, bh, acc); acc = MFMA(a1l, bh, acc); acc = MFMA(a1h, bl, acc);
            sa[nt] = acc;
        }
        float scl[4];
#pragma unroll
        for (int j = 0; j < 4; j++) {
            float m0 = fmaxf(fmaxf(sa[0][j], sa[1][j]), fmaxf(sa[2][j], sa[3][j]));
            m0 = fmaxf(m0, __shfl_xor(m0, 1)); m0 = fmaxf(m0, __shfl_xor(m0, 2));
            m0 = fmaxf(m0, __shfl_xor(m0, 4)); m0 = fmaxf(m0, __shfl_xor(m0, 8));
            float mnew = fmaxf(mrow[j], m0);
            float sc = __expf(mrow[j] - mnew);
            float ps = 0.f;
#pragma unroll
            for (int nt = 0; nt < 4; nt++) {
                float p = __expf(sa[nt][j] - mnew);
                sa[nt][j] = p; ps += p;
            }
            ps += __shfl_xor(ps, 1); ps += __shfl_xor(ps, 2);
            ps += __shfl_xor(ps, 4); ps += __shfl_xor(ps, 8);
            srow[j] = srow[j] * sc + ps;
            mrow[j] = mnew;
            scl[j] = sc;
        }
#pragma unroll
        for (int dt = 0; dt < 4; dt++)
#pragma unroll
            for (int j = 0; j < 4; j++) rv[dt][j] *= scl[j];
#pragma unroll
        for (int nt = 0; nt < 4; nt++)
#pragma unroll
            for (int j = 0; j < 4; j++) {
                u16 h, l; splitbf(sa[nt][j], h, l);
                stb16(Ph, mrow0 + j, 16 * nt + lrow, h);
                stb16(Pl, mrow0 + j, 16 * nt + lrow, l);
            }
        __syncthreads();
        short8 p0h = ldfrag(Ph, 16 * w + lrow, lk);
        short8 p0l = ldfrag(Pl, 16 * w + lrow, lk);
        short8 p1h = ldfrag(Ph, 16 * w + lrow, 32 + lk);
        short8 p1l = ldfrag(Pl, 16 * w + lrow, 32 + lk);
#pragma unroll
        for (int dt = 0; dt < 4; dt++) {
            short8 bh = ldfrag(Vth, 16 * dt + lrow, lk);
            short8 bl = ldfrag(Vtl, 16 * dt + lrow, lk);
            rv[dt] = MFMA(p0h, bh, rv[dt]); rv[dt] = MFMA(p0l, bh, rv[dt]); rv[dt] = MFMA(p0h, bl, rv[dt]);
            bh = ldfrag(Vth, 16 * dt + lrow, 32 + lk);
            bl = ldfrag(Vtl, 16 * dt + lrow, 32 + lk);
            rv[dt] = MFMA(p1h, bh, rv[dt]); rv[dt] = MFMA(p1l, bh, rv[dt]); rv[dt] = MFMA(p1h, bl, rv[dt]);
        }
    }
    size_t pb = (size_t)(head * 8 + ch) * 64;
    if (lrow == 0) {
#pragma unroll
        for (int j = 0; j < 4; j++) {
            ws[OFF_PMAX + pb + mrow0 + j] = mrow[j];
            ws[OFF_PSUM + pb + mrow0 + j] = srow[j];
        }
    }
#pragma unroll
    for (int dt = 0; dt < 4; dt++)
#pragma unroll
        for (int j = 0; j < 4; j++)
            ws[OFF_PRV + (pb + mrow0 + j) * 64 + 16 * dt + lrow] = rv[dt][j];
}

// ---------- kernel G: combine partials -> RV; W = k2inv @ RV; write W^T bf16 ----------
__global__ __launch_bounds__(256) void k_comb(float* ws) {
    int head = blockIdx.x, t = threadIdx.x;
    __shared__ __align__(16) float A_s[4096];
    __shared__ __align__(16) float B_s[4096];
    loadT64(A_s, ws + OFF_VM + (size_t)head * 4096, t);
    int ti = t >> 4, tj = t & 15, i0 = ti << 2, j0 = tj << 2;
    const float* pm = ws + OFF_PMAX + (size_t)head * 512;
    const float* psv = ws + OFF_PSUM + (size_t)head * 512;
    const float* prv = ws + OFF_PRV + (size_t)head * 8 * 4096;
    float gm[4] = {-INFINITY, -INFINITY, -INFINITY, -INFINITY};
    for (int c8 = 0; c8 < 8; c8++)
#pragma unroll
        for (int r = 0; r < 4; r++) gm[r] = fmaxf(gm[r], pm[c8 * 64 + i0 + r]);
    float stot[4] = {0.f, 0.f, 0.f, 0.f};
    float racc[4][4];
#pragma unroll
    for (int r = 0; r < 4; r++)
#pragma unroll
        for (int c = 0; c < 4; c++) racc[r][c] = 0.f;
    for (int c8 = 0; c8 < 8; c8++) {
#pragma unroll
        for (int r = 0; r < 4; r++) {
            float w = __expf(pm[c8 * 64 + i0 + r] - gm[r]);
            stot[r] += w * psv[c8 * 64 + i0 + r];
            float4 v = *(const float4*)(prv + (size_t)(c8 * 64 + i0 + r) * 64 + j0);
            racc[r][0] += w * v.x; racc[r][1] += w * v.y;
            racc[r][2] += w * v.z; racc[r][3] += w * v.w;
        }
    }
#pragma unroll
    for (int r = 0; r < 4; r++)
#pragma unroll
        for (int c = 0; c < 4; c++) racc[r][c] /= stot[r];
    writeN64(B_s, racc, i0, j0, 1.f);
    __syncthreads();
    float acc[4][4];
    mm64(A_s, B_s, acc, i0, j0);
    u16* wth = (u16*)(ws + OFF_WTH) + (size_t)head * 4096;
    u16* wtl = (u16*)(ws + OFF_WTL) + (size_t)head * 4096;
#pragma unroll
    for (int r = 0; r < 4; r++)
#pragma unroll
        for (int c = 0; c < 4; c++) {
            u16 h, l; splitbf(acc[r][c], h, l);
            wth[(j0 + c) * 64 + (i0 + r)] = h;   // W^T[d][n]
            wtl[(j0 + c) * 64 + (i0 + r)] = l;
        }
}

// ---------- kernel H: X = softmax(Q@nc^T/8) @ W — MFMA split-bf16 ----------
__global__ __launch_bounds__(256) void k_final(const float* __restrict__ Qg, float* ws,
                                               float* __restrict__ out) {
    int tile = blockIdx.x, head = blockIdx.y, t = threadIdx.x;
    __shared__ __align__(16) u16 Ah[4096], Al[4096];   // Q then P
    __shared__ __align__(16) u16 Bh[4096], Bl[4096];   // nc then W^T
    __shared__ __align__(16) float C[64 * 68];
    const float* Qt = Qg + ((size_t)head * NSEQ + (size_t)tile * 64) * 64;
    stage64(Qt, Ah, Al, t, 0.125f);
    copy64bf(Bh, (const u16*)(ws + OFF_NCH) + (size_t)head * 4096, t);
    copy64bf(Bl, (const u16*)(ws + OFF_NCL) + (size_t)head * 4096, t);
    __syncthreads();
    int w = t >> 6, lane = t & 63, lrow = lane & 15, lk = (lane >> 4) << 3;
    int mrow0 = 16 * w + ((lane >> 4) << 2);
    short8 a0h = ldfrag(Ah, 16 * w + lrow, lk);
    short8 a0l = ldfrag(Al, 16 * w + lrow, lk);
    short8 a1h = ldfrag(Ah, 16 * w + lrow, 32 + lk);
    short8 a1l = ldfrag(Al, 16 * w + lrow, 32 + lk);
    f32x4 sa[4];
#pragma unroll
    for (int nt = 0; nt < 4; nt++) {
        f32x4 acc = (f32x4){0.f, 0.f, 0.f, 0.f};
        short8 bh = ldfrag(Bh, 16 * nt + lrow, lk);
        short8 bl = ldfrag(Bl, 16 * nt + lrow, lk);
        acc = MFMA(a0h, bh, acc); acc = MFMA(a0l, bh, acc); acc = MFMA(a0h, bl, acc);
        bh = ldfrag(Bh, 16 * nt + lrow, 32 + lk);
        bl = ldfrag(Bl, 16 * nt + lrow, 32 + lk);
        acc = MFMA(a1h, bh, acc); acc = MFMA(a1l, bh, acc); acc = MFMA(a1h, bl, acc);
        sa[nt] = acc;
    }
#pragma unroll
    for (int j = 0; j < 4; j++) {
        float m0 = fmaxf(fmaxf(sa[0][j], sa[1][j]), fmaxf(sa[2][j], sa[3][j]));
        m0 = fmaxf(m0, __shfl_xor(m0, 1)); m0 = fmaxf(m0, __shfl_xor(m0, 2));
        m0 = fmaxf(m0, __shfl_xor(m0, 4)); m0 = fmaxf(m0, __shfl_xor(m0, 8));
        float ps = 0.f;
#pragma unroll
        for (int nt = 0; nt < 4; nt++) {
            float p = __expf(sa[nt][j] - m0);
            sa[nt][j] = p; ps += p;
        }
        ps += __shfl_xor(ps, 1); ps += __shfl_xor(ps, 2);
        ps += __shfl_xor(ps, 4); ps += __shfl_xor(ps, 8);
        float inv = 1.f / ps;
#pragma unroll
        for (int nt = 0; nt < 4; nt++) sa[nt][j] *= inv;
    }
    __syncthreads();                           // done reading Q/nc from LDS
#pragma unroll
    for (int nt = 0; nt < 4; nt++)
#pragma unroll
        for (int j = 0; j < 4; j++) {
            u16 h, l; splitbf(sa[nt][j], h, l);
            stb16(Ah, mrow0 + j, 16 * nt + lrow, h);
            stb16(Al, mrow0 + j, 16 * nt + lrow, l);
        }
    copy64bf(Bh, (const u16*)(ws + OFF_WTH) + (size_t)head * 4096, t);
    copy64bf(Bl, (const u16*)(ws + OFF_WTL) + (size_t)head * 4096, t);
    __syncthreads();
    short8 p0h = ldfrag(Ah, 16 * w + lrow, lk);
    short8 p0l = ldfrag(Al, 16 * w + lrow, lk);
    short8 p1h = ldfrag(Ah, 16 * w + lrow, 32 + lk);
    short8 p1l = ldfrag(Al, 16 * w + lrow, 32 + lk);
#pragma unroll
    for (int dt = 0; dt < 4; dt++) {
        f32x4 x = (f32x4){0.f, 0.f, 0.f, 0.f};
        short8 bh = ldfrag(Bh, 16 * dt + lrow, lk);
        short8 bl = ldfrag(Bl, 16 * dt + lrow, lk);
        x = MFMA(p0h, bh, x); x = MFMA(p0l, bh, x); x = MFMA(p0h, bl, x);
        bh = ldfrag(Bh, 16 * dt + lrow, 32 + lk);
        bl = ldfrag(Bl, 16 * dt + lrow, 32 + lk);
        x = MFMA(p1h, bh, x); x = MFMA(p1l, bh, x); x = MFMA(p1h, bl, x);
#pragma unroll
        for (int j = 0; j < 4; j++) C[(mrow0 + j) * 68 + 16 * dt + lrow] = x[j];
    }
    __syncthreads();
    float* op = out + ((size_t)head * NSEQ + (size_t)tile * 64) * 64;
#pragma unroll
    for (int i = 0; i < 4; i++) {
        int e = t + 256 * i;
        int row = e >> 4, c0 = (e & 15) << 2;
        *(float4*)(op + row * 64 + c0) = *(const float4*)(C + row * 68 + c0);
    }
}

// ---------- launcher ----------
extern "C" void kernel_launch(void* const* d_in, const int* in_sizes, int n_in,
                              void* d_out, int out_size, void* d_ws, size_t ws_size,
                              hipStream_t stream) {
    const float* Q = (const float*)d_in[0];
    const float* K = (const float*)d_in[1];
    const float* V = (const float*)d_in[2];
    float* ws = (float*)d_ws;
    float* out = (float*)d_out;

    k_sums<<<4096, 256, 0, stream>>>(Q, K, ws);
    k_select<<<dim3(64, 2), 256, 0, stream>>>(Q, K, ws);
    k_u<<<64, 256, 0, stream>>>(ws);
    k_rvp<<<dim3(64, 8), 256, 0, stream>>>(K, V, ws);
    k_nsinv<<<64, 256, 0, stream>>>(ws);
    k_comb<<<64, 256, 0, stream>>>(ws);
    k_final<<<dim3(64, 64), 256, 0, stream>>>(Q, ws, out);
}

// Round 4
// 158.683 us; speedup vs baseline: 2.0846x; 1.2450x over previous
//
#include <hip/hip_runtime.h>
#include <math.h>

// Problem constants: B=8, H=8 (BH=64 heads), N=4096, D=64, M=64, 6 NS iters.
#define NSEQ 4096

// workspace offsets (in float units). Total high-water ~16.0 MB.
#define OFF_SUMK 0u        // 262144  (k_sums -> k_select)
#define OFF_SUMQ 262144u   // 262144  (k_sums -> k_select)
#define OFF_WTH  0u        // bf16 W^T hi (k_comb -> k_final)
#define OFF_WTL  131072u
#define OFF_U    262144u   // (k_u -> k_nsinv)
#define OFF_NC   524288u   // f32 nc  (k_select -> k_u)
#define OFF_NR   786432u   // f32 nr  (k_select -> k_u)
#define OFF_VM   1048576u  // k_nsinv -> k_comb
#define OFF_NCH  1310720u  // bf16 arrays (k_select -> k_rvp/k_final)
#define OFF_NCL  1441792u
#define OFF_NRH  1572864u
#define OFF_NRL  1703936u
#define OFF_PMAX 1835008u  // 64*8*64
#define OFF_PSUM 1867776u
#define OFF_HMAX 1900544u
#define OFF_PRV  1900672u  // 64*8*64*64 = 2097152 -> end 3997824 floats

typedef unsigned short u16;
typedef short short8 __attribute__((ext_vector_type(8)));
typedef float f32x4 __attribute__((ext_vector_type(4)));

// ---------------- bf16 split helpers ----------------
__device__ __forceinline__ u16 f2bf(float x) {      // RNE f32->bf16 bits
    unsigned u = __float_as_uint(x);
    unsigned r = (u + 0x7FFFu + ((u >> 16) & 1u)) >> 16;
    return (u16)r;
}
__device__ __forceinline__ void splitbf(float x, u16& h, u16& l) {
    unsigned u = __float_as_uint(x);
    h = (u16)(u >> 16);                              // truncate -> exact residual
    float hf = __uint_as_float(u & 0xFFFF0000u);
    l = f2bf(x - hf);
}

// ---------------- swizzled LDS tile helpers (64x64 bf16, 128B rows) ----------------
__device__ __forceinline__ short8 ldfrag(const u16* base, int row, int k0) {
    int byte = (row << 7) + (k0 << 1);
    byte ^= (row & 7) << 4;
    return *(const short8*)((const char*)base + byte);
}
__device__ __forceinline__ void st4(u16* base, int row, int c0, ushort4 v) {
    int byte = (row << 7) + (c0 << 1);
    byte ^= (row & 7) << 4;
    *(ushort4*)((char*)base + byte) = v;
}
__device__ __forceinline__ void stb16(u16* base, int row, int c, u16 v) {
    int byte = (row << 7) + (c << 1);
    byte ^= (row & 7) << 4;
    *(u16*)((char*)base + byte) = v;
}

__device__ __forceinline__ f32x4 MFMA(short8 a, short8 b, f32x4 c) {
    return __builtin_amdgcn_mfma_f32_16x16x32_bf16(a, b, c, 0, 0, 0);
}

// C[m][n] = sum_k A[m][k]*B_arr[n][k], split-bf16 3-product.
// Output: cv[nt][j] = C[mrow0+j][16*nt+lrow]
__device__ __forceinline__ void mfma_mm(const u16* AH, const u16* AL,
                                        const u16* BH, const u16* BL,
                                        f32x4 cv[4], int w, int lrow, int lk) {
    short8 a0h = ldfrag(AH, 16 * w + lrow, lk);
    short8 a0l = ldfrag(AL, 16 * w + lrow, lk);
    short8 a1h = ldfrag(AH, 16 * w + lrow, 32 + lk);
    short8 a1l = ldfrag(AL, 16 * w + lrow, 32 + lk);
#pragma unroll
    for (int nt = 0; nt < 4; nt++) {
        f32x4 acc = (f32x4){0.f, 0.f, 0.f, 0.f};
        short8 bh = ldfrag(BH, 16 * nt + lrow, lk);
        short8 bl = ldfrag(BL, 16 * nt + lrow, lk);
        acc = MFMA(a0h, bh, acc); acc = MFMA(a0l, bh, acc); acc = MFMA(a0h, bl, acc);
        bh = ldfrag(BH, 16 * nt + lrow, 32 + lk);
        bl = ldfrag(BL, 16 * nt + lrow, 32 + lk);
        acc = MFMA(a1h, bh, acc); acc = MFMA(a1l, bh, acc); acc = MFMA(a1h, bl, acc);
        cv[nt] = acc;
    }
}

// stage 64x64 f32 global tile (row-major) -> hi/lo bf16 LDS, swizzled rows
__device__ __forceinline__ void stage64(const float* __restrict__ g, u16* Lh, u16* Ll,
                                        int t, float scale) {
#pragma unroll
    for (int i = 0; i < 4; i++) {
        int e = t + 256 * i;
        int row = e >> 4, c0 = (e & 15) << 2;
        float4 v = *(const float4*)(g + row * 64 + c0);
        float vv[4] = {v.x * scale, v.y * scale, v.z * scale, v.w * scale};
        ushort4 h, l;
        splitbf(vv[0], h.x, l.x); splitbf(vv[1], h.y, l.y);
        splitbf(vv[2], h.z, l.z); splitbf(vv[3], h.w, l.w);
        st4(Lh, row, c0, h); st4(Ll, row, c0, l);
    }
}

// stage 64x64 f32 global tile TRANSPOSED -> Lh/Ll[d][n] bf16, swizzled rows
__device__ __forceinline__ void stageT64(const float* __restrict__ g, u16* Lh, u16* Ll, int t) {
#pragma unroll
    for (int i = 0; i < 4; i++) {
        int e = t + 256 * i;
        int n = e >> 4, d0 = (e & 15) << 2;
        float4 v = *(const float4*)(g + n * 64 + d0);
        float vv[4] = {v.x, v.y, v.z, v.w};
#pragma unroll
        for (int k = 0; k < 4; k++) {
            u16 h, l; splitbf(vv[k], h, l);
            stb16(Lh, d0 + k, n, h); stb16(Ll, d0 + k, n, l);
        }
    }
}

// copy 64x64 bf16 (row-major in global) -> swizzled LDS
__device__ __forceinline__ void copy64bf(u16* dst, const u16* __restrict__ src, int t) {
#pragma unroll
    for (int i = 0; i < 4; i++) {
        int e = t + 256 * i;
        int row = e >> 4, c0 = (e & 15) << 2;
        ushort4 v = *(const ushort4*)(src + row * 64 + c0);
        st4(dst, row, c0, v);
    }
}

// ---------------- f32 64x64 VALU matmul helpers (small kernels) ----------------
__device__ __forceinline__ void loadT64(float* dst, const float* __restrict__ src, int t) {
    for (int e = t; e < 1024; e += 256) {
        int m = e >> 4, k0 = (e & 15) << 2;
        float4 v = *(const float4*)(src + m * 64 + k0);
        dst[(k0 + 0) * 64 + m] = v.x;
        dst[(k0 + 1) * 64 + m] = v.y;
        dst[(k0 + 2) * 64 + m] = v.z;
        dst[(k0 + 3) * 64 + m] = v.w;
    }
}
__device__ __forceinline__ void mm64add(const float* Acm, const float* Brm,
                                        float acc[4][4], int i0, int j0) {
#pragma unroll 8
    for (int k = 0; k < 64; k++) {
        float4 a = *(const float4*)(Acm + k * 64 + i0);
        float4 b = *(const float4*)(Brm + k * 64 + j0);
        acc[0][0] += a.x * b.x; acc[0][1] += a.x * b.y; acc[0][2] += a.x * b.z; acc[0][3] += a.x * b.w;
        acc[1][0] += a.y * b.x; acc[1][1] += a.y * b.y; acc[1][2] += a.y * b.z; acc[1][3] += a.y * b.w;
        acc[2][0] += a.z * b.x; acc[2][1] += a.z * b.y; acc[2][2] += a.z * b.z; acc[2][3] += a.z * b.w;
        acc[3][0] += a.w * b.x; acc[3][1] += a.w * b.y; acc[3][2] += a.w * b.z; acc[3][3] += a.w * b.w;
    }
}
__device__ __forceinline__ void mm64(const float* Acm, const float* Brm,
                                     float acc[4][4], int i0, int j0) {
#pragma unroll
    for (int r = 0; r < 4; r++)
#pragma unroll
        for (int c = 0; c < 4; c++) acc[r][c] = 0.f;
    mm64add(Acm, Brm, acc, i0, j0);
}
__device__ __forceinline__ void writeN64(float* dst, const float acc[4][4], int i0, int j0, float s) {
#pragma unroll
    for (int r = 0; r < 4; r++) {
        float4 v;
        v.x = s * acc[r][0]; v.y = s * acc[r][1]; v.z = s * acc[r][2]; v.w = s * acc[r][3];
        *(float4*)(dst + (i0 + r) * 64 + j0) = v;
    }
}

// ---------- kernel A: row sums of Q and K ----------
__global__ __launch_bounds__(256) void k_sums(const float* __restrict__ Qg,
                                              const float* __restrict__ Kg, float* ws) {
    size_t row = (size_t)blockIdx.x * 64 + (threadIdx.x >> 2);
    int q = threadIdx.x & 3;
    const float4* qp = (const float4*)(Qg + row * 64 + q * 16);
    const float4* kp = (const float4*)(Kg + row * 64 + q * 16);
    float s1 = 0.f, s2 = 0.f;
#pragma unroll
    for (int i = 0; i < 4; i++) { float4 v = qp[i]; s1 += (v.x + v.y) + (v.z + v.w); }
#pragma unroll
    for (int i = 0; i < 4; i++) { float4 v = kp[i]; s2 += (v.x + v.y) + (v.z + v.w); }
    s1 += __shfl_xor(s1, 1); s1 += __shfl_xor(s1, 2);
    s2 += __shfl_xor(s2, 1); s2 += __shfl_xor(s2, 2);
    if (q == 0) { ws[OFF_SUMQ + row] = s1; ws[OFF_SUMK + row] = s2; }
}

// ---------- kernel B: top-64 select via MSB radix-select + gather ----------
__global__ __launch_bounds__(256) void k_select(const float* __restrict__ Qg,
                                                const float* __restrict__ Kg, float* ws) {
    int head = blockIdx.x, sel = blockIdx.y, t = threadIdx.x;
    __shared__ int hist[257];
    __shared__ int idx_s[64];
    __shared__ unsigned s_prefix;
    __shared__ int s_need, s_cnt, s_win;
    __shared__ int wred[4];
    const float* scores = ws + (sel ? OFF_SUMQ : OFF_SUMK) + (size_t)head * 4096;
    unsigned uu[16];
#pragma unroll
    for (int i = 0; i < 16; i++) {
        unsigned u = __float_as_uint(scores[t + 256 * i]);
        uu[i] = (u & 0x80000000u) ? ~u : (u | 0x80000000u);
    }
    if (t == 0) { s_prefix = 0u; s_need = 64; }
    __syncthreads();
#pragma unroll
    for (int p = 0; p < 4; p++) {
        hist[t] = 0;
        if (t == 0) hist[256] = 0;
        __syncthreads();
        unsigned pref = s_prefix;
        int sh = 32 - 8 * p;
        int dsh = 24 - 8 * p;
#pragma unroll
        for (int i = 0; i < 16; i++) {
            bool active = (p == 0) || ((uu[i] >> sh) == (pref >> sh));
            if (active) atomicAdd(&hist[(uu[i] >> dsh) & 255], 1);
        }
        __syncthreads();
        // suffix scan: hist[t] = sum_{x>=t} count
        for (int s = 1; s < 256; s <<= 1) {
            int v = (t + s < 256) ? hist[t + s] : 0;
            __syncthreads();
            hist[t] += v;
            __syncthreads();
        }
        int need = s_need;
        __syncthreads();
        if (hist[t] >= need && (t == 255 || hist[t + 1] < need)) {
            s_need = need - ((t == 255) ? 0 : hist[t + 1]);
            s_prefix = pref | ((unsigned)t << dsh);
        }
        __syncthreads();
    }
    unsigned thr = s_prefix;
    int needEq = s_need;
    if (t == 0) s_cnt = 0;
    __syncthreads();
    unsigned eqm = 0;
#pragma unroll
    for (int i = 0; i < 16; i++) {
        if (uu[i] > thr) { int pos = atomicAdd(&s_cnt, 1); idx_s[pos] = t + 256 * i; }
        else if (uu[i] == thr) eqm |= (1u << i);
    }
    __syncthreads();
    int base = 64 - needEq;
    int lane = t & 63, wid = t >> 6;
    for (int r = 0; r < needEq; r++) {
        int mymin = 0x7FFFFFFF;
#pragma unroll
        for (int i = 0; i < 16; i++)
            if ((eqm >> i) & 1) mymin = min(mymin, t + 256 * i);
#pragma unroll
        for (int s = 1; s < 64; s <<= 1) mymin = min(mymin, __shfl_xor(mymin, s));
        if (lane == 0) wred[wid] = mymin;
        __syncthreads();
        if (t == 0) {
            int wv = min(min(wred[0], wred[1]), min(wred[2], wred[3]));
            s_win = wv;
            idx_s[base + r] = wv;
        }
        __syncthreads();
        int wv = s_win;
        if ((wv & 255) == t) eqm &= ~(1u << (wv >> 8));
        __syncthreads();
    }
    // gather selected rows
    const float* src = sel ? Qg : Kg;
    float* dst = ws + (sel ? OFF_NR : OFF_NC) + (size_t)head * 4096;
    u16* dh = (u16*)(ws + (sel ? OFF_NRH : OFF_NCH)) + (size_t)head * 4096;
    u16* dl = (u16*)(ws + (sel ? OFF_NRL : OFF_NCL)) + (size_t)head * 4096;
    float scl = sel ? 0.125f : 1.0f;
    for (int e = t; e < 4096; e += 256) {
        int m = e >> 6, d = e & 63;
        float v = src[((size_t)head * NSEQ + (size_t)idx_s[m]) * 64 + d] * scl;
        dst[e] = v;
        u16 h, l; splitbf(v, h, l);
        dh[e] = h; dl[e] = l;
    }
}

// ---------- kernel C: u = softmax(nr @ nc^T) + per-head max colsum ----------
__global__ __launch_bounds__(256) void k_u(float* ws) {
    int head = blockIdx.x, t = threadIdx.x;
    __shared__ __align__(16) float A_s[4096];
    __shared__ __align__(16) float B_s[4096];
    __shared__ float colpart[1024];
    loadT64(A_s, ws + OFF_NR + (size_t)head * 4096, t);
    loadT64(B_s, ws + OFF_NC + (size_t)head * 4096, t);
    __syncthreads();
    int ti = t >> 4, tj = t & 15, i0 = ti << 2, j0 = tj << 2;
    float acc[4][4];
    mm64(A_s, B_s, acc, i0, j0);
#pragma unroll
    for (int r = 0; r < 4; r++) {
        float m0 = fmaxf(fmaxf(acc[r][0], acc[r][1]), fmaxf(acc[r][2], acc[r][3]));
        m0 = fmaxf(m0, __shfl_xor(m0, 1)); m0 = fmaxf(m0, __shfl_xor(m0, 2));
        m0 = fmaxf(m0, __shfl_xor(m0, 4)); m0 = fmaxf(m0, __shfl_xor(m0, 8));
        float s = 0.f;
#pragma unroll
        for (int c = 0; c < 4; c++) { acc[r][c] = __expf(acc[r][c] - m0); s += acc[r][c]; }
        s += __shfl_xor(s, 1); s += __shfl_xor(s, 2);
        s += __shfl_xor(s, 4); s += __shfl_xor(s, 8);
#pragma unroll
        for (int c = 0; c < 4; c++) acc[r][c] = acc[r][c] / s;
    }
    float* u = ws + OFF_U + (size_t)head * 4096;
#pragma unroll
    for (int r = 0; r < 4; r++) {
        float4 v; v.x = acc[r][0]; v.y = acc[r][1]; v.z = acc[r][2]; v.w = acc[r][3];
        *(float4*)(u + (i0 + r) * 64 + j0) = v;
    }
#pragma unroll
    for (int c = 0; c < 4; c++)
        colpart[ti * 64 + j0 + c] = acc[0][c] + acc[1][c] + acc[2][c] + acc[3][c];
    __syncthreads();
    if (t < 64) {
        float cs = 0.f;
#pragma unroll
        for (int g = 0; g < 16; g++) cs += colpart[g * 64 + t];
        float v = cs;
#pragma unroll
        for (int s = 1; s < 64; s <<= 1) v = fmaxf(v, __shfl_xor(v, s));
        if (t == 0) ws[OFF_HMAX + head] = v;
    }
}

// ---------- kernel E: Newton-Schulz inverse via MFMA split-bf16 ----------
__global__ __launch_bounds__(256) void k_nsinv(float* ws) {
    int head = blockIdx.x, t = threadIdx.x;
    __shared__ __align__(16) u16 KmH[4096], KmL[4096];   // Km, N layout
    __shared__ __align__(16) u16 VmNH[4096], VmNL[4096]; // Vm, N layout
    __shared__ __align__(16) u16 VmTH[4096], VmTL[4096]; // Vm^T layout (B-operand)
    __shared__ __align__(16) u16 KVH[4096], KVL[4096];   // KV, N layout
    __shared__ __align__(16) u16 BtH[4096], BtL[4096];   // rotating B-operand (T layout)
    __shared__ __align__(16) float Vmf[4096];            // Vm f32 row-major (unswizzled)

    int w = t >> 6, lane = t & 63, lrow = lane & 15, lk = (lane >> 4) << 3;
    int mrow0 = 16 * w + ((lane >> 4) << 2);

    // global max over per-head colsum maxima (fold of old k_gmax)
    float g = ws[OFF_HMAX + lane];
#pragma unroll
    for (int s = 1; s < 64; s <<= 1) g = fmaxf(g, __shfl_xor(g, s));
    float ginv = 1.0f / g;

    // init: Km = u;  Vm = u^T/g  (VmT layout == u/g row-major)
    const float* u = ws + OFF_U + (size_t)head * 4096;
#pragma unroll
    for (int i = 0; i < 4; i++) {
        int e = t + 256 * i;
        int row = e >> 4, c0 = (e & 15) << 2;
        float4 v = *(const float4*)(u + row * 64 + c0);
        float vv[4] = {v.x, v.y, v.z, v.w};
        ushort4 h4, l4;
        splitbf(vv[0], h4.x, l4.x); splitbf(vv[1], h4.y, l4.y);
        splitbf(vv[2], h4.z, l4.z); splitbf(vv[3], h4.w, l4.w);
        st4(KmH, row, c0, h4); st4(KmL, row, c0, l4);
        float sv[4] = {vv[0] * ginv, vv[1] * ginv, vv[2] * ginv, vv[3] * ginv};
        splitbf(sv[0], h4.x, l4.x); splitbf(sv[1], h4.y, l4.y);
        splitbf(sv[2], h4.z, l4.z); splitbf(sv[3], h4.w, l4.w);
        st4(VmTH, row, c0, h4); st4(VmTL, row, c0, l4);
#pragma unroll
        for (int k = 0; k < 4; k++) {
            u16 h, l; splitbf(sv[k], h, l);
            stb16(VmNH, c0 + k, row, h); stb16(VmNL, c0 + k, row, l);
            Vmf[(c0 + k) * 64 + row] = sv[k];
        }
    }
    __syncthreads();

    f32x4 cv[4];
    for (int it = 0; it < 6; it++) {
        // s1: KV = Km @ Vm   (A=KmN, B=VmT); store KVN and Bt=(7I-KV)^T (disjoint arrays)
        mfma_mm(KmH, KmL, VmTH, VmTL, cv, w, lrow, lk);
#pragma unroll
        for (int nt = 0; nt < 4; nt++)
#pragma unroll
            for (int j = 0; j < 4; j++) {
                int m = mrow0 + j, n = 16 * nt + lrow;
                float v = cv[nt][j];
                u16 h, l; splitbf(v, h, l);
                stb16(KVH, m, n, h); stb16(KVL, m, n, l);
                float b = ((m == n) ? 7.f : 0.f) - v;
                splitbf(b, h, l);
                stb16(BtH, n, m, h); stb16(BtL, n, m, l);
            }
        __syncthreads();
        // s2: M2 = KV @ M1;  Bt' = (15I - M2)^T
        mfma_mm(KVH, KVL, BtH, BtL, cv, w, lrow, lk);
        __syncthreads();
#pragma unroll
        for (int nt = 0; nt < 4; nt++)
#pragma unroll
            for (int j = 0; j < 4; j++) {
                int m = mrow0 + j, n = 16 * nt + lrow;
                float b = ((m == n) ? 15.f : 0.f) - cv[nt][j];
                u16 h, l; splitbf(b, h, l);
                stb16(BtH, n, m, h); stb16(BtL, n, m, l);
            }
        __syncthreads();
        // s3: M4 = KV @ M3;  Bt'' = (13I - M4)^T
        mfma_mm(KVH, KVL, BtH, BtL, cv, w, lrow, lk);
        __syncthreads();
#pragma unroll
        for (int nt = 0; nt < 4; nt++)
#pragma unroll
            for (int j = 0; j < 4; j++) {
                int m = mrow0 + j, n = 16 * nt + lrow;
                float b = ((m == n) ? 13.f : 0.f) - cv[nt][j];
                u16 h, l; splitbf(b, h, l);
                stb16(BtH, n, m, h); stb16(BtL, n, m, l);
            }
        __syncthreads();
        // s4: Vm' = 0.25 * Vm @ M5   (A=VmN, B=Bt)
        mfma_mm(VmNH, VmNL, BtH, BtL, cv, w, lrow, lk);
        __syncthreads();
#pragma unroll
        for (int nt = 0; nt < 4; nt++)
#pragma unroll
            for (int j = 0; j < 4; j++) {
                int m = mrow0 + j, n = 16 * nt + lrow;
                float v = 0.25f * cv[nt][j];
                u16 h, l; splitbf(v, h, l);
                stb16(VmNH, m, n, h); stb16(VmNL, m, n, l);
                stb16(VmTH, n, m, h); stb16(VmTL, n, m, l);
                Vmf[m * 64 + n] = v;
            }
        __syncthreads();
    }

    float* vm = ws + OFF_VM + (size_t)head * 4096;
#pragma unroll
    for (int i = 0; i < 4; i++) {
        int e = t + 256 * i;
        int row = e >> 4, c0 = (e & 15) << 2;
        *(float4*)(vm + row * 64 + c0) = *(const float4*)(Vmf + row * 64 + c0);
    }
}

// ---------- kernel F: flash softmax(nr@K^T)@V partials — MFMA split-bf16 ----------
__global__ __launch_bounds__(256) void k_rvp(const float* __restrict__ Kg,
                                             const float* __restrict__ Vg, float* ws) {
    int head = blockIdx.x, ch = blockIdx.y, t = threadIdx.x;
    __shared__ __align__(16) u16 NRh[4096], NRl[4096];
    __shared__ __align__(16) u16 Kh[4096], Kl[4096];
    __shared__ __align__(16) u16 Ph[4096], Pl[4096];
    __shared__ __align__(16) u16 Vth[4096], Vtl[4096];
    const u16* nrh = (const u16*)(ws + OFF_NRH) + (size_t)head * 4096;
    const u16* nrl = (const u16*)(ws + OFF_NRL) + (size_t)head * 4096;
    copy64bf(NRh, nrh, t);
    copy64bf(NRl, nrl, t);
    int w = t >> 6, lane = t & 63, lrow = lane & 15, lk = (lane >> 4) << 3;
    int mrow0 = 16 * w + ((lane >> 4) << 2);
    __syncthreads();
    // loop-invariant A fragments (nr)
    short8 a0h = ldfrag(NRh, 16 * w + lrow, lk);
    short8 a0l = ldfrag(NRl, 16 * w + lrow, lk);
    short8 a1h = ldfrag(NRh, 16 * w + lrow, 32 + lk);
    short8 a1l = ldfrag(NRl, 16 * w + lrow, 32 + lk);
    f32x4 rv[4];
#pragma unroll
    for (int dt = 0; dt < 4; dt++) rv[dt] = (f32x4){0.f, 0.f, 0.f, 0.f};
    float mrow[4] = {-INFINITY, -INFINITY, -INFINITY, -INFINITY};
    float srow[4] = {0.f, 0.f, 0.f, 0.f};
    const float* Kb = Kg + ((size_t)head * NSEQ + (size_t)ch * 512) * 64;
    const float* Vb = Vg + ((size_t)head * NSEQ + (size_t)ch * 512) * 64;
    for (int s8 = 0; s8 < 8; s8++) {
        __syncthreads();                       // prior reads of Kh/Vt/Ph complete
        stage64(Kb + s8 * 4096, Kh, Kl, t, 1.0f);
        stageT64(Vb + s8 * 4096, Vth, Vtl, t);
        __syncthreads();
        f32x4 sa[4];
#pragma unroll
        for (int nt = 0; nt < 4; nt++) {
            f32x4 acc = (f32x4){0.f, 0.f, 0.f, 0.f};
            short8 bh = ldfrag(Kh, 16 * nt + lrow, lk);
            short8 bl = ldfrag(Kl, 16 * nt + lrow, lk);
            acc = MFMA(a0h, bh, acc); acc = MFMA(a0l, bh, acc); acc = MFMA(a0h, bl, acc);
            bh = ldfrag(Kh, 16 * nt + lrow, 32 + lk);
            bl = ldfrag(Kl, 16 * nt + lrow, 32 + lk);
            acc = MFMA(a1h, bh, acc); acc = MFMA(a1l, bh, acc); acc = MFMA(a1h, bl, acc);
            sa[nt] = acc;
        }
        float scl[4];
#pragma unroll
        for (int j = 0; j < 4; j++) {
            float m0 = fmaxf(fmaxf(sa[0][j], sa[1][j]), fmaxf(sa[2][j], sa[3][j]));
            m0 = fmaxf(m0, __shfl_xor(m0, 1)); m0 = fmaxf(m0, __shfl_xor(m0, 2));
            m0 = fmaxf(m0, __shfl_xor(m0, 4)); m0 = fmaxf(m0, __shfl_xor(m0, 8));
            float mnew = fmaxf(mrow[j], m0);
            float sc = __expf(mrow[j] - mnew);
            float ps = 0.f;
#pragma unroll
            for (int nt = 0; nt < 4; nt++) {
                float p = __expf(sa[nt][j] - mnew);
                sa[nt][j] = p; ps += p;
            }
            ps += __shfl_xor(ps, 1); ps += __shfl_xor(ps, 2);
            ps += __shfl_xor(ps, 4); ps += __shfl_xor(ps, 8);
            srow[j] = srow[j] * sc + ps;
            mrow[j] = mnew;
            scl[j] = sc;
        }
#pragma unroll
        for (int dt = 0; dt < 4; dt++)
#pragma unroll
            for (int j = 0; j < 4; j++) rv[dt][j] *= scl[j];
#pragma unroll
        for (int nt = 0; nt < 4; nt++)
#pragma unroll
            for (int j = 0; j < 4; j++) {
                u16 h, l; splitbf(sa[nt][j], h, l);
                stb16(Ph, mrow0 + j, 16 * nt + lrow, h);
                stb16(Pl, mrow0 + j, 16 * nt + lrow, l);
            }
        __syncthreads();
        short8 p0h = ldfrag(Ph, 16 * w + lrow, lk);
        short8 p0l = ldfrag(Pl, 16 * w + lrow, lk);
        short8 p1h = ldfrag(Ph, 16 * w + lrow, 32 + lk);
        short8 p1l = ldfrag(Pl, 16 * w + lrow, 32 + lk);
#pragma unroll
        for (int dt = 0; dt < 4; dt++) {
            short8 bh = ldfrag(Vth, 16 * dt + lrow, lk);
            short8 bl = ldfrag(Vtl, 16 * dt + lrow, lk);
            rv[dt] = MFMA(p0h, bh, rv[dt]); rv[dt] = MFMA(p0l, bh, rv[dt]); rv[dt] = MFMA(p0h, bl, rv[dt]);
            bh = ldfrag(Vth, 16 * dt + lrow, 32 + lk);
            bl = ldfrag(Vtl, 16 * dt + lrow, 32 + lk);
            rv[dt] = MFMA(p1h, bh, rv[dt]); rv[dt] = MFMA(p1l, bh, rv[dt]); rv[dt] = MFMA(p1h, bl, rv[dt]);
        }
    }
    size_t pb = (size_t)(head * 8 + ch) * 64;
    if (lrow == 0) {
#pragma unroll
        for (int j = 0; j < 4; j++) {
            ws[OFF_PMAX + pb + mrow0 + j] = mrow[j];
            ws[OFF_PSUM + pb + mrow0 + j] = srow[j];
        }
    }
#pragma unroll
    for (int dt = 0; dt < 4; dt++)
#pragma unroll
        for (int j = 0; j < 4; j++)
            ws[OFF_PRV + (pb + mrow0 + j) * 64 + 16 * dt + lrow] = rv[dt][j];
}

// ---------- kernel G: combine partials -> RV; W = k2inv @ RV; write W^T bf16 ----------
__global__ __launch_bounds__(256) void k_comb(float* ws) {
    int head = blockIdx.x, t = threadIdx.x;
    __shared__ __align__(16) float A_s[4096];
    __shared__ __align__(16) float B_s[4096];
    loadT64(A_s, ws + OFF_VM + (size_t)head * 4096, t);
    int ti = t >> 4, tj = t & 15, i0 = ti << 2, j0 = tj << 2;
    const float* pm = ws + OFF_PMAX + (size_t)head * 512;
    const float* psv = ws + OFF_PSUM + (size_t)head * 512;
    const float* prv = ws + OFF_PRV + (size_t)head * 8 * 4096;
    float gm[4] = {-INFINITY, -INFINITY, -INFINITY, -INFINITY};
    for (int c8 = 0; c8 < 8; c8++)
#pragma unroll
        for (int r = 0; r < 4; r++) gm[r] = fmaxf(gm[r], pm[c8 * 64 + i0 + r]);
    float stot[4] = {0.f, 0.f, 0.f, 0.f};
    float racc[4][4];
#pragma unroll
    for (int r = 0; r < 4; r++)
#pragma unroll
        for (int c = 0; c < 4; c++) racc[r][c] = 0.f;
    for (int c8 = 0; c8 < 8; c8++) {
#pragma unroll
        for (int r = 0; r < 4; r++) {
            float w = __expf(pm[c8 * 64 + i0 + r] - gm[r]);
            stot[r] += w * psv[c8 * 64 + i0 + r];
            float4 v = *(const float4*)(prv + (size_t)(c8 * 64 + i0 + r) * 64 + j0);
            racc[r][0] += w * v.x; racc[r][1] += w * v.y;
            racc[r][2] += w * v.z; racc[r][3] += w * v.w;
        }
    }
#pragma unroll
    for (int r = 0; r < 4; r++)
#pragma unroll
        for (int c = 0; c < 4; c++) racc[r][c] /= stot[r];
    writeN64(B_s, racc, i0, j0, 1.f);
    __syncthreads();
    float acc[4][4];
    mm64(A_s, B_s, acc, i0, j0);
    u16* wth = (u16*)(ws + OFF_WTH) + (size_t)head * 4096;
    u16* wtl = (u16*)(ws + OFF_WTL) + (size_t)head * 4096;
#pragma unroll
    for (int r = 0; r < 4; r++)
#pragma unroll
        for (int c = 0; c < 4; c++) {
            u16 h, l; splitbf(acc[r][c], h, l);
            wth[(j0 + c) * 64 + (i0 + r)] = h;   // W^T[d][n]
            wtl[(j0 + c) * 64 + (i0 + r)] = l;
        }
}

// ---------- kernel H: X = softmax(Q@nc^T/8) @ W — MFMA split-bf16 ----------
__global__ __launch_bounds__(256) void k_final(const float* __restrict__ Qg, float* ws,
                                               float* __restrict__ out) {
    int tile = blockIdx.x, head = blockIdx.y, t = threadIdx.x;
    __shared__ __align__(16) u16 Ah[4096], Al[4096];   // Q then P
    __shared__ __align__(16) u16 Bh[4096], Bl[4096];   // nc then W^T
    __shared__ __align__(16) float C[64 * 68];
    const float* Qt = Qg + ((size_t)head * NSEQ + (size_t)tile * 64) * 64;
    stage64(Qt, Ah, Al, t, 0.125f);
    copy64bf(Bh, (const u16*)(ws + OFF_NCH) + (size_t)head * 4096, t);
    copy64bf(Bl, (const u16*)(ws + OFF_NCL) + (size_t)head * 4096, t);
    __syncthreads();
    int w = t >> 6, lane = t & 63, lrow = lane & 15, lk = (lane >> 4) << 3;
    int mrow0 = 16 * w + ((lane >> 4) << 2);
    short8 a0h = ldfrag(Ah, 16 * w + lrow, lk);
    short8 a0l = ldfrag(Al, 16 * w + lrow, lk);
    short8 a1h = ldfrag(Ah, 16 * w + lrow, 32 + lk);
    short8 a1l = ldfrag(Al, 16 * w + lrow, 32 + lk);
    f32x4 sa[4];
#pragma unroll
    for (int nt = 0; nt < 4; nt++) {
        f32x4 acc = (f32x4){0.f, 0.f, 0.f, 0.f};
        short8 bh = ldfrag(Bh, 16 * nt + lrow, lk);
        short8 bl = ldfrag(Bl, 16 * nt + lrow, lk);
        acc = MFMA(a0h, bh, acc); acc = MFMA(a0l, bh, acc); acc = MFMA(a0h, bl, acc);
        bh = ldfrag(Bh, 16 * nt + lrow, 32 + lk);
        bl = ldfrag(Bl, 16 * nt + lrow, 32 + lk);
        acc = MFMA(a1h, bh, acc); acc = MFMA(a1l, bh, acc); acc = MFMA(a1h, bl, acc);
        sa[nt] = acc;
    }
#pragma unroll
    for (int j = 0; j < 4; j++) {
        float m0 = fmaxf(fmaxf(sa[0][j], sa[1][j]), fmaxf(sa[2][j], sa[3][j]));
        m0 = fmaxf(m0, __shfl_xor(m0, 1)); m0 = fmaxf(m0, __shfl_xor(m0, 2));
        m0 = fmaxf(m0, __shfl_xor(m0, 4)); m0 = fmaxf(m0, __shfl_xor(m0, 8));
        float ps = 0.f;
#pragma unroll
        for (int nt = 0; nt < 4; nt++) {
            float p = __expf(sa[nt][j] - m0);
            sa[nt][j] = p; ps += p;
        }
        ps += __shfl_xor(ps, 1); ps += __shfl_xor(ps, 2);
        ps += __shfl_xor(ps, 4); ps += __shfl_xor(ps, 8);
        float inv = 1.f / ps;
#pragma unroll
        for (int nt = 0; nt < 4; nt++) sa[nt][j] *= inv;
    }
    __syncthreads();                           // done reading Q/nc from LDS
#pragma unroll
    for (int nt = 0; nt < 4; nt++)
#pragma unroll
        for (int j = 0; j < 4; j++) {
            u16 h, l; splitbf(sa[nt][j], h, l);
            stb16(Ah, mrow0 + j, 16 * nt + lrow, h);
            stb16(Al, mrow0 + j, 16 * nt + lrow, l);
        }
    copy64bf(Bh, (const u16*)(ws + OFF_WTH) + (size_t)head * 4096, t);
    copy64bf(Bl, (const u16*)(ws + OFF_WTL) + (size_t)head * 4096, t);
    __syncthreads();
    short8 p0h = ldfrag(Ah, 16 * w + lrow, lk);
    short8 p0l = ldfrag(Al, 16 * w + lrow, lk);
    short8 p1h = ldfrag(Ah, 16 * w + lrow, 32 + lk);
    short8 p1l = ldfrag(Al, 16 * w + lrow, 32 + lk);
#pragma unroll
    for (int dt = 0; dt < 4; dt++) {
        f32x4 x = (f32x4){0.f, 0.f, 0.f, 0.f};
        short8 bh = ldfrag(Bh, 16 * dt + lrow, lk);
        short8 bl = ldfrag(Bl, 16 * dt + lrow, lk);
        x = MFMA(p0h, bh, x); x = MFMA(p0l, bh, x); x = MFMA(p0h, bl, x);
        bh = ldfrag(Bh, 16 * dt + lrow, 32 + lk);
        bl = ldfrag(Bl, 16 * dt + lrow, 32 + lk);
        x = MFMA(p1h, bh, x); x = MFMA(p1l, bh, x); x = MFMA(p1h, bl, x);
#pragma unroll
        for (int j = 0; j < 4; j++) C[(mrow0 + j) * 68 + 16 * dt + lrow] = x[j];
    }
    __syncthreads();
    float* op = out + ((size_t)head * NSEQ + (size_t)tile * 64) * 64;
#pragma unroll
    for (int i = 0; i < 4; i++) {
        int e = t + 256 * i;
        int row = e >> 4, c0 = (e & 15) << 2;
        *(float4*)(op + row * 64 + c0) = *(const float4*)(C + row * 68 + c0);
    }
}

// ---------- launcher ----------
extern "C" void kernel_launch(void* const* d_in, const int* in_sizes, int n_in,
                              void* d_out, int out_size, void* d_ws, size_t ws_size,
                              hipStream_t stream) {
    const float* Q = (const float*)d_in[0];
    const float* K = (const float*)d_in[1];
    const float* V = (const float*)d_in[2];
    float* ws = (float*)d_ws;
    float* out = (float*)d_out;

    k_sums<<<4096, 256, 0, stream>>>(Q, K, ws);
    k_select<<<dim3(64, 2), 256, 0, stream>>>(Q, K, ws);
    k_u<<<64, 256, 0, stream>>>(ws);
    k_rvp<<<dim3(64, 8), 256, 0, stream>>>(K, V, ws);
    k_nsinv<<<64, 256, 0, stream>>>(ws);
    k_comb<<<64, 256, 0, stream>>>(ws);
    k_final<<<dim3(64, 64), 256, 0, stream>>>(Q, ws, out);
}